// Round 7
// baseline (541.225 us; speedup 1.0000x reference)
//
#include <hip/hip_runtime.h>
#include <hip/hip_bf16.h>
#include <math.h>

typedef __attribute__((ext_vector_type(8))) short bf16x8;
typedef __attribute__((ext_vector_type(4))) float f32x4;

// ---------------- |w|^2 per filter row ----------------
__global__ __launch_bounds__(256) void sw2_kernel(
    const float* __restrict__ w1, const float* __restrict__ w2,
    const float* __restrict__ w3,
    float* __restrict__ s1, float* __restrict__ s2, float* __restrict__ s3) {
  int t = blockIdx.x * blockDim.x + threadIdx.x;
  if (t < 192) {
    const float* r = w1 + t * 25;
    float s = 0.f;
    for (int i = 0; i < 25; i++) s += r[i] * r[i];
    s1[t] = s;
  } else if (t < 192 + 384) {
    int u = t - 192;
    const float* r = w2 + u * 576;
    float s = 0.f;
    for (int i = 0; i < 576; i++) s += r[i] * r[i];
    s2[u] = s;
  } else if (t < 192 + 384 + 768) {
    int u = t - 576;
    const float* r = w3 + u * 1152;
    float s = 0.f;
    for (int i = 0; i < 1152; i++) s += r[i] * r[i];
    s3[u] = s;
  }
}

// ---------------- transpose conv weights (layer1 only) ---------------------
__global__ __launch_bounds__(256) void tr_w_kernel(
    const float* __restrict__ in, float* __restrict__ out, int O, int K) {
  int idx = blockIdx.x * blockDim.x + threadIdx.x;
  int total = 3 * O * K;
  if (idx >= total) return;
  int o = idx % O;
  int r = idx / O;
  int k = r % K;
  int br = r / K;
  out[((size_t)br * K + k) * O + o] = in[((size_t)br * O + o) * K + k];
}

// ---------------- transpose fc_w: [oo][br][c][pth] -> [oo][br][pth][c] -----
__global__ __launch_bounds__(256) void tr_fcw_kernel(
    const float* __restrict__ fcw, float* __restrict__ fcwt) {
  int tb = blockIdx.x;  // 18 pth-tiles x 8 c-tiles
  int pt = tb % 18, ct = tb / 18;
  int ob = blockIdx.y;  // oo*3+br
  __shared__ float tile[32][33];
  const float* src = fcw + (size_t)ob * 147456;
  float* dst = fcwt + (size_t)ob * 147456;
  int tx = threadIdx.x, ty = threadIdx.y;  // (32,8)
  int pth0 = pt * 32, c0 = ct * 32;
  for (int i = 0; i < 32; i += 8) {
    int c = c0 + ty + i;
    tile[ty + i][tx] = src[(size_t)c * 576 + pth0 + tx];
  }
  __syncthreads();
  for (int i = 0; i < 32; i += 8) {
    int pth = pth0 + ty + i;
    dst[(size_t)pth * 256 + c0 + tx] = tile[tx][ty + i];
  }
}

// ---------------- pack weights into MFMA-fragment layout, split hi/lo ------
template <int CIN, int COUT>
__global__ __launch_bounds__(256) void pack_w_kernel(
    const float* __restrict__ w, unsigned short* __restrict__ bph,
    unsigned short* __restrict__ bpl) {
  constexpr int K = CIN * 9;
  constexpr int CC = CIN / 32;
  const int n = blockIdx.x, br = blockIdx.z;
  const int t = threadIdx.x;
  __shared__ float row[K];
  const float* src = w + ((size_t)br * COUT + n) * K;
  for (int i = t; i < K; i += 256) row[i] = src[i];
  __syncthreads();
  for (int i = t; i < K; i += 256) {
    int kpos = i / CIN;
    int e = i - kpos * CIN;  // = c
    float f = row[e * 9 + kpos];
    __hip_bfloat16 h = __float2bfloat16(f);
    float hf = __bfloat162float(h);
    __hip_bfloat16 l = __float2bfloat16(f - hf);
    size_t oidx =
        (((size_t)br * 9 * CC + (size_t)kpos * CC + (e >> 5)) * COUT + n) * 32 +
        (e & 31);
    bph[oidx] = *reinterpret_cast<unsigned short*>(&h);
    bpl[oidx] = *reinterpret_cast<unsigned short*>(&l);
  }
}

// ---------------- Layer 1: 1ch 5x5 pad2 -> 64ch, crelu(rank31), pool -------
// 256 threads = 4 waves; block covers 8x8 conv pixels (4x4 pool outputs);
// wave w handles conv rows 2w..2w+1. Threshold via 4-fused wave radix-select
// (ballot+popcount bisection on the positive-float bit pattern).
__global__ __launch_bounds__(256) void layer1_kernel(
    const float* __restrict__ x,    // [16][3][96][96]
    const float* __restrict__ w1t,  // [3][25][64]
    const float* __restrict__ sw2v, // [3][64]
    const float* __restrict__ tri,  // [3][3]
    float* __restrict__ a1)         // [3][16][48][48][64]
{
  const int gidx = blockIdx.x;  // 12 x 12 tiles
  const int gy = gidx / 12, gx = gidx % 12;
  const int n = blockIdx.y, br = blockIdx.z;
  const int t = threadIdx.x;
  const int lane = t & 63, wid = t >> 6;

  __shared__ __align__(16) float win[12][12];
  __shared__ float sp2s[64];

  const int y0 = gy * 8 - 2, x0 = gx * 8 - 2;
  const float* xb = x + ((size_t)(n * 3 + br)) * 96 * 96;
  if (t < 144) {
    int wy = t / 12, wx = t - (t / 12) * 12;
    int y = y0 + wy, xx = x0 + wx;
    float v = 0.f;
    if (y >= 0 && y < 96 && xx >= 0 && xx < 96) v = xb[y * 96 + xx];
    win[wy][wx] = v;
  }
  __syncthreads();

  if (t < 64) {
    int py = t >> 3, px = t & 7;
    float s = 0.f;
#pragma unroll
    for (int ky = 0; ky < 5; ky++)
#pragma unroll
      for (int kx = 0; kx < 5; kx++) {
        float v = win[py + ky][px + kx];
        s += v * v;
      }
    sp2s[t] = s;
  }
  __syncthreads();

  const float* wb = w1t + br * 25 * 64 + lane;
  float wv[25];
#pragma unroll
  for (int j = 0; j < 25; j++) wv[j] = wb[j * 64];

  float acc[2][8] = {};
#pragma unroll
  for (int wyy = 0; wyy < 6; wyy++) {
    const int wy = wid * 2 + wyy;
    float4 ra = *reinterpret_cast<const float4*>(&win[wy][0]);
    float4 rb = *reinterpret_cast<const float4*>(&win[wy][4]);
    float4 rc = *reinterpret_cast<const float4*>(&win[wy][8]);
    float r[12] = {ra.x, ra.y, ra.z, ra.w, rb.x, rb.y,
                   rb.z, rb.w, rc.x, rc.y, rc.z, rc.w};
#pragma unroll
    for (int py = 0; py < 2; py++) {
      int ky = wyy - py;
      if (ky < 0 || ky > 4) continue;
#pragma unroll
      for (int kx = 0; kx < 5; kx++) {
        float wvv = wv[ky * 5 + kx];
#pragma unroll
        for (int px = 0; px < 8; px++) acc[py][px] += wvv * r[px + kx];
      }
    }
  }

  const float sw = sw2v[br * 64 + lane];
  const float w_ = tri[br * 3 + 0];

  float dv[16];
#pragma unroll
  for (int p = 0; p < 16; p++) {
    const int py = p >> 3, px = p & 7;
    float d2 = sp2s[(wid * 2 + py) * 8 + px] + sw - 2.f * acc[py][px];
    dv[p] = sqrtf(fmaxf(d2, 1e-12f));
  }

  // 4-fused radix select (rank 31 of 64) -> wave-uniform thresholds
  float thrv[16];
#pragma unroll
  for (int g = 0; g < 4; g++) {
    unsigned int key[4], pre[4];
    int rem[4];
#pragma unroll
    for (int j = 0; j < 4; j++) {
      key[j] = __float_as_uint(dv[g * 4 + j]);
      pre[j] = 0u;
      rem[j] = 31;
    }
    for (int b = 30; b >= 0; --b) {
#pragma unroll
      for (int j = 0; j < 4; j++) {
        unsigned int top = (pre[j] >> b) | 1u;
        int cnt = __popcll(__ballot((key[j] >> b) == top));
        if (cnt > rem[j]) pre[j] |= (1u << b);
        else rem[j] -= cnt;
      }
    }
#pragma unroll
    for (int j = 0; j < 4; j++) thrv[g * 4 + j] = __uint_as_float(pre[j]);
  }

  const float A2[2][2] = {{0.9f, 0.93f}, {0.96f, 0.99f}};
  float pooled[4] = {0.f, 0.f, 0.f, 0.f};
#pragma unroll
  for (int p = 0; p < 16; p++) {
    const int py = p >> 3, px = p & 7;
    float th = fminf(thrv[p], w_);
    float a = 1.f - ((dv[p] > th) ? w_ : dv[p]) / w_;
    pooled[px >> 1] += a * A2[py][px & 1];
  }
#pragma unroll
  for (int g = 0; g < 4; g++) {
    a1[((((size_t)(br * 16 + n)) * 48 + (gy * 4 + wid)) * 48 + (gx * 4 + g)) *
           64 + lane] = pooled[g] * 0.25f;
  }
}

// ---------------- Layers 2/3: MFMA split-bf16 RBF conv ---------------------
// 256 threads = 4 waves; block covers 4 rows x 8 cols of conv pixels.
// Each wave owns COUT/4 filters (ng = wave id) and ALL 32 pixels (mt 0/1).
// B fragments double-buffered in registers.
template <int CIN, int COUT, int HIN, int KRANK, int POOL, int LIDX>
__global__ __launch_bounds__(256) void mfma_rbf3(
    const float* __restrict__ in,            // [3][16][HIN][HIN][CIN]
    const unsigned short* __restrict__ bph,  // packed hi
    const unsigned short* __restrict__ bpl,  // packed lo
    const float* __restrict__ sw2v,          // [3][COUT]
    const float* __restrict__ tri,
    float* __restrict__ out) {
  constexpr int CC = CIN / 32;
  constexpr int NCH = 9 * CC;               // K chunks of 32
  constexpr int NT = COUT / 16;
  constexpr int NTW = NT / 4;               // N tiles per wave
  constexpr int PADC = COUT + 4;
  constexpr int WIN_USH = 60 * CIN;         // per buffer (h or l)
  constexpr int WIN_BYTES = 2 * WIN_USH * 2;
  constexpr int DMAT_BYTES = 32 * PADC * 4;
  constexpr int UNI_BYTES = WIN_BYTES > DMAT_BYTES ? WIN_BYTES : DMAT_BYTES;

  __shared__ __align__(16) char uni[UNI_BYTES];
  __shared__ float cellq[60][4];
  __shared__ float cellsum[60];
  __shared__ float sp2[32];
  __shared__ float thrs[32];
  __shared__ float sw2s[COUT];

  unsigned short* winh = (unsigned short*)uni;
  unsigned short* winl = winh + WIN_USH;
  float* dmat = (float*)uni;  // aliases win after conv

  const int GX = HIN / 8;
  const int gy = blockIdx.x / GX, gx = blockIdx.x % GX;
  const int n = blockIdx.y, br = blockIdx.z;
  const int t = threadIdx.x;
  const int lane = t & 63;
  const int wvid = t >> 6;
  const int ng = wvid;  // N quarter

  const float w_ = tri[br * 3 + LIDX];
  const int y0 = gy * 4 - 1, x0 = gx * 8 - 1;
  const float* ib = in + ((size_t)(br * 16 + n)) * HIN * HIN * CIN;

  // ---- stage window (fp32 -> bf16 hi/lo, swizzled) + cell partial sums ----
  for (int i = t; i < COUT; i += 256) sw2s[i] = sw2v[br * COUT + i];
  if (t < 240) {
    const int cell = t >> 2, q = t & 3;
    const int wy = cell / 10, wx = cell - (cell / 10) * 10;
    const int y = y0 + wy, xx = x0 + wx;
    const bool ok = (y >= 0 && y < HIN && xx >= 0 && xx < HIN);
    const float* rp = ib + ((size_t)y * HIN + xx) * CIN + q * (CIN / 4);
    const int sx = (wx & 7) << 3;
    float ss = 0.f;
#pragma unroll
    for (int cq = 0; cq < CIN / 16; cq++) {
      float4 v = ok ? *reinterpret_cast<const float4*>(rp + cq * 4)
                    : make_float4(0.f, 0.f, 0.f, 0.f);
      unsigned short hh[4], ll[4];
      float fv[4] = {v.x, v.y, v.z, v.w};
#pragma unroll
      for (int j = 0; j < 4; j++) {
        float f = fv[j];
        ss += f * f;
        __hip_bfloat16 h = __float2bfloat16(f);
        float hf = __bfloat162float(h);
        __hip_bfloat16 l = __float2bfloat16(f - hf);
        hh[j] = *reinterpret_cast<unsigned short*>(&h);
        ll[j] = *reinterpret_cast<unsigned short*>(&l);
      }
      int c = q * (CIN / 4) + cq * 4;
      int cst = c ^ sx;
      *reinterpret_cast<ushort4*>(&winh[cell * CIN + cst]) =
          make_ushort4(hh[0], hh[1], hh[2], hh[3]);
      *reinterpret_cast<ushort4*>(&winl[cell * CIN + cst]) =
          make_ushort4(ll[0], ll[1], ll[2], ll[3]);
    }
    cellq[cell][q] = ss;
  }
  __syncthreads();
  if (t < 60)
    cellsum[t] = cellq[t][0] + cellq[t][1] + cellq[t][2] + cellq[t][3];
  __syncthreads();
  if (t < 32) {
    int py = t >> 3, px = t & 7;
    float s = 0.f;
#pragma unroll
    for (int ky = 0; ky < 3; ky++)
#pragma unroll
      for (int kx = 0; kx < 3; kx++) s += cellsum[(py + ky) * 10 + px + kx];
    sp2[t] = s;
  }

  // ---- conv: D[pixel][filter], 3-term split bf16, reg-dbuf B pipeline ----
  const int pix0 = lane & 15;
  const int g8 = (lane >> 4) << 3;
  const int ppy = pix0 >> 3, ppx = pix0 & 7;

  f32x4 acc[2][NTW];
  f32x4 zz = {0.f, 0.f, 0.f, 0.f};
#pragma unroll
  for (int mt = 0; mt < 2; mt++)
#pragma unroll
    for (int nt = 0; nt < NTW; nt++) acc[mt][nt] = zz;

  const size_t bbase = (size_t)br * NCH;
  const int nb0 = ng * (NTW * 16) + pix0;

  bf16x8 bufA[2 * NTW], bufB[2 * NTW];

  auto loadB = [&](int chunk, bf16x8* dst) {
    const unsigned short* p0 =
        bph + ((bbase + chunk) * COUT + nb0) * 32 + g8;
    const unsigned short* p1 =
        bpl + ((bbase + chunk) * COUT + nb0) * 32 + g8;
#pragma unroll
    for (int nt = 0; nt < NTW; nt++) {
      dst[2 * nt] = *reinterpret_cast<const bf16x8*>(p0 + nt * 512);
      dst[2 * nt + 1] = *reinterpret_cast<const bf16x8*>(p1 + nt * 512);
    }
  };

  auto compute = [&](int chunk, bf16x8* b) {
    const int kpos = chunk / CC, cc = chunk - (chunk / CC) * CC;
    const int ky = kpos / 3, kx = kpos - (kpos / 3) * 3;
    const int wx = ppx + kx;
    const int sx = (wx & 7) << 3;
    const int cbase = ((cc << 5) + g8) ^ sx;
#pragma unroll
    for (int mt = 0; mt < 2; mt++) {
      const int r0 = (mt * 2 + ppy + ky) * 10 + wx;
      bf16x8 ah = *reinterpret_cast<const bf16x8*>(&winh[r0 * CIN + cbase]);
      bf16x8 al = *reinterpret_cast<const bf16x8*>(&winl[r0 * CIN + cbase]);
#pragma unroll
      for (int nt = 0; nt < NTW; nt++) {
        acc[mt][nt] = __builtin_amdgcn_mfma_f32_16x16x32_bf16(
            ah, b[2 * nt], acc[mt][nt], 0, 0, 0);
        acc[mt][nt] = __builtin_amdgcn_mfma_f32_16x16x32_bf16(
            ah, b[2 * nt + 1], acc[mt][nt], 0, 0, 0);
        acc[mt][nt] = __builtin_amdgcn_mfma_f32_16x16x32_bf16(
            al, b[2 * nt], acc[mt][nt], 0, 0, 0);
      }
    }
  };

  loadB(0, bufA);
  for (int ch = 0; ch < NCH; ch += 2) {
    loadB(ch + 1, bufB);
    compute(ch, bufA);
    if (ch + 2 < NCH) loadB(ch + 2, bufA);
    compute(ch + 1, bufB);
  }

  __syncthreads();  // conv reads of win done (alias!), sp2 visible

  // ---- d = sqrt(|p|^2 + |w|^2 - 2 dot) into dmat -------------------------
  const int rgrp = (lane >> 4) << 2;
#pragma unroll
  for (int mt = 0; mt < 2; mt++) {
    const int prow = mt * 16 + rgrp;
#pragma unroll
    for (int nt = 0; nt < NTW; nt++) {
      const int col = ng * (NTW * 16) + nt * 16 + pix0;
      const float sw = sw2s[col];
#pragma unroll
      for (int rg = 0; rg < 4; rg++) {
        const int pix = prow + rg;
        float d2 = sp2[pix] + sw - 2.f * acc[mt][nt][rg];
        dmat[pix * PADC + col] = sqrtf(fmaxf(d2, 1e-12f));
      }
    }
  }
  __syncthreads();

  // ---- per-pixel top-k threshold: radix select, 2 pixels fused for ILP ---
  for (int i = 0; i < 8; i += 2) {
    const int p0 = wvid * 8 + i, p1 = p0 + 1;
    unsigned int a0, a1v, a2, a3, b0, b1, b2, b3;
    if constexpr (COUT == 256) {
      float4 fa = *reinterpret_cast<const float4*>(&dmat[p0 * PADC + lane * 4]);
      float4 fb = *reinterpret_cast<const float4*>(&dmat[p1 * PADC + lane * 4]);
      a0 = __float_as_uint(fa.x); a1v = __float_as_uint(fa.y);
      a2 = __float_as_uint(fa.z); a3 = __float_as_uint(fa.w);
      b0 = __float_as_uint(fb.x); b1 = __float_as_uint(fb.y);
      b2 = __float_as_uint(fb.z); b3 = __float_as_uint(fb.w);
    } else {
      float2 fa = *reinterpret_cast<const float2*>(&dmat[p0 * PADC + lane * 2]);
      float2 fb = *reinterpret_cast<const float2*>(&dmat[p1 * PADC + lane * 2]);
      a0 = __float_as_uint(fa.x); a1v = __float_as_uint(fa.y);
      b0 = __float_as_uint(fb.x); b1 = __float_as_uint(fb.y);
      a2 = a3 = b2 = b3 = 0;
    }
    unsigned int pre0 = 0, pre1 = 0;
    int rem0 = KRANK, rem1 = KRANK;
    for (int b = 30; b >= 0; --b) {
      unsigned int top0 = (pre0 >> b) | 1u;
      unsigned int top1 = (pre1 >> b) | 1u;
      int c0 = __popcll(__ballot((a0 >> b) == top0)) +
               __popcll(__ballot((a1v >> b) == top0));
      int c1 = __popcll(__ballot((b0 >> b) == top1)) +
               __popcll(__ballot((b1 >> b) == top1));
      if constexpr (COUT == 256) {
        c0 += __popcll(__ballot((a2 >> b) == top0)) +
              __popcll(__ballot((a3 >> b) == top0));
        c1 += __popcll(__ballot((b2 >> b) == top1)) +
              __popcll(__ballot((b3 >> b) == top1));
      }
      if (c0 > rem0) pre0 |= (1u << b); else rem0 -= c0;
      if (c1 > rem1) pre1 |= (1u << b); else rem1 -= c1;
    }
    if (lane == 0) {
      thrs[p0] = __uint_as_float(pre0);
      thrs[p1] = __uint_as_float(pre1);
    }
  }
  __syncthreads();

  // ---- activation (+ pool) + store ---------------------------------------
  if (POOL) {
    const int GW = HIN / 2;
    float* ob = out + ((size_t)(br * 16 + n)) * GW * GW * COUT;
    for (int i = t; i < 8 * COUT; i += 256) {
      int q = i / COUT;
      int ch = i - q * COUT;
      int qy = q >> 2, qx = q & 3;
      int p00 = qy * 16 + qx * 2;
      float d00 = dmat[p00 * PADC + ch];
      float d01 = dmat[(p00 + 1) * PADC + ch];
      float d10 = dmat[(p00 + 8) * PADC + ch];
      float d11 = dmat[(p00 + 9) * PADC + ch];
      float t00 = fminf(thrs[p00], w_);
      float t01 = fminf(thrs[p00 + 1], w_);
      float t10 = fminf(thrs[p00 + 8], w_);
      float t11 = fminf(thrs[p00 + 9], w_);
      float a00 = 1.f - ((d00 > t00) ? w_ : d00) / w_;
      float a01 = 1.f - ((d01 > t01) ? w_ : d01) / w_;
      float a10 = 1.f - ((d10 > t10) ? w_ : d10) / w_;
      float a11 = 1.f - ((d11 > t11) ? w_ : d11) / w_;
      float po =
          0.25f * (a00 * 0.9f + a01 * 0.93f + a10 * 0.96f + a11 * 0.99f);
      ob[((size_t)((gy * 2 + qy) * GW + gx * 4 + qx)) * COUT + ch] = po;
    }
  } else {
    float* ob = out + ((size_t)(br * 16 + n)) * HIN * HIN * COUT;
    for (int i = 0; i < 8; i++) {
      int r = wvid * 8 + i;
      float4 dv = *reinterpret_cast<const float4*>(&dmat[r * PADC + lane * 4]);
      float th = fminf(thrs[r], w_);
      float4 av;
      av.x = 1.f - ((dv.x > th) ? w_ : dv.x) / w_;
      av.y = 1.f - ((dv.y > th) ? w_ : dv.y) / w_;
      av.z = 1.f - ((dv.z > th) ? w_ : dv.z) / w_;
      av.w = 1.f - ((dv.w > th) ? w_ : dv.w) / w_;
      int oy = gy * 4 + (r >> 3), ox = gx * 8 + (r & 7);
      *reinterpret_cast<float4*>(
          &ob[((size_t)(oy * HIN + ox)) * COUT + lane * 4]) = av;
    }
  }
}

// ---------------- FC: split-K partials + reduce ----------------------------
__global__ __launch_bounds__(256) void fc_partial_kernel(
    const float* __restrict__ feats, const float* __restrict__ fcwt,
    float* __restrict__ partial) {
  const int oo = blockIdx.x;  // 0..9
  const int n = blockIdx.y;   // 0..15
  const int s = blockIdx.z;   // 0..7
  const int t = threadIdx.x;
  const int i0 = s * 4608;
  float acc = 0.f;
  for (int br = 0; br < 3; br++) {
    const float4* fb = reinterpret_cast<const float4*>(
        feats + ((size_t)(br * 16 + n)) * 147456);
    const float4* wb = reinterpret_cast<const float4*>(
        fcwt + ((size_t)(oo * 3 + br)) * 147456);
    for (int i = i0 + t; i < i0 + 4608; i += 256) {
      float4 f = fb[i], w = wb[i];
      acc += f.x * w.x + f.y * w.y + f.z * w.z + f.w * w.w;
    }
  }
  __shared__ float red[256];
  red[t] = acc;
  __syncthreads();
  for (int st = 128; st > 0; st >>= 1) {
    if (t < st) red[t] += red[t + st];
    __syncthreads();
  }
  if (t == 0) partial[((size_t)oo * 16 + n) * 8 + s] = red[0];
}

__global__ __launch_bounds__(256) void fc_final_kernel(
    const float* __restrict__ partial, const float* __restrict__ fcb,
    float* __restrict__ outp) {
  const int t = threadIdx.x;
  if (t < 160) {
    int oo = t / 16, n = t % 16;
    float s = 0.f;
#pragma unroll
    for (int q = 0; q < 8; q++) s += partial[((size_t)oo * 16 + n) * 8 + q];
    outp[n * 10 + oo] = s + fcb[oo];
  }
}

// ---------------------------------------------------------------------------
extern "C" void kernel_launch(void* const* d_in, const int* in_sizes, int n_in,
                              void* d_out, int out_size, void* d_ws,
                              size_t ws_size, hipStream_t stream) {
  const float* x   = (const float*)d_in[0];
  const float* w1  = (const float*)d_in[1];
  const float* w2  = (const float*)d_in[2];
  const float* w3  = (const float*)d_in[3];
  const float* tri = (const float*)d_in[4];
  const float* fcw = (const float*)d_in[5];
  const float* fcb = (const float*)d_in[6];
  float* out = (float*)d_out;

  float* ws = (float*)d_ws;
  float* a1    = ws;                  // 7,077,888
  float* a2    = a1 + 7077888;        // 3,538,944
  float* feats = a2 + 3538944;        // 7,077,888
  float* s1    = feats + 7077888;     // 192
  float* s2    = s1 + 192;            // 384
  float* s3    = s2 + 384;            // 768
  float* w1t   = s3 + 768;            // 4,800
  unsigned short* bph2 = (unsigned short*)(w1t + 4800);  // 221,184 ushorts
  unsigned short* bpl2 = bph2 + 221184;
  unsigned short* bph3 = bpl2 + 221184;                  // 884,736
  unsigned short* bpl3 = bph3 + 884736;
  float* partial = (float*)(bpl3 + 884736);              // 1,280 floats
  float* fcwt = a1;  // aliases a1 (dead after layer2)

  tr_w_kernel<<<dim3(19), dim3(256), 0, stream>>>(w1, w1t, 64, 25);
  sw2_kernel<<<dim3(6), dim3(256), 0, stream>>>(w1, w2, w3, s1, s2, s3);
  pack_w_kernel<64, 128><<<dim3(128, 1, 3), dim3(256), 0, stream>>>(w2, bph2,
                                                                    bpl2);
  pack_w_kernel<128, 256><<<dim3(256, 1, 3), dim3(256), 0, stream>>>(w3, bph3,
                                                                     bpl3);

  layer1_kernel<<<dim3(144, 16, 3), dim3(256), 0, stream>>>(x, w1t, s1, tri,
                                                            a1);
  mfma_rbf3<64, 128, 48, 63, 1, 1>
      <<<dim3(72, 16, 3), dim3(256), 0, stream>>>(a1, bph2, bpl2, s2, tri, a2);
  // a1 dead; reuse for transposed fc weights
  tr_fcw_kernel<<<dim3(144, 30), dim3(32, 8), 0, stream>>>(fcw, fcwt);
  mfma_rbf3<128, 256, 24, 152, 0, 2>
      <<<dim3(18, 16, 3), dim3(256), 0, stream>>>(a2, bph3, bpl3, s3, tri,
                                                  feats);
  fc_partial_kernel<<<dim3(10, 16, 8), dim3(256), 0, stream>>>(feats, fcwt,
                                                               partial);
  fc_final_kernel<<<dim3(1), dim3(256), 0, stream>>>(partial, fcb, out);
}

// Round 8
// 194.017 us; speedup vs baseline: 2.7896x; 2.7896x over previous
//
#include <hip/hip_runtime.h>
#include <hip/hip_bf16.h>
#include <math.h>

typedef __attribute__((ext_vector_type(8))) short bf16x8;
typedef __attribute__((ext_vector_type(4))) float f32x4;

// ---------------- |w|^2 per filter row ----------------
__global__ __launch_bounds__(256) void sw2_kernel(
    const float* __restrict__ w1, const float* __restrict__ w2,
    const float* __restrict__ w3,
    float* __restrict__ s1, float* __restrict__ s2, float* __restrict__ s3) {
  int t = blockIdx.x * blockDim.x + threadIdx.x;
  if (t < 192) {
    const float* r = w1 + t * 25;
    float s = 0.f;
    for (int i = 0; i < 25; i++) s += r[i] * r[i];
    s1[t] = s;
  } else if (t < 192 + 384) {
    int u = t - 192;
    const float* r = w2 + u * 576;
    float s = 0.f;
    for (int i = 0; i < 576; i++) s += r[i] * r[i];
    s2[u] = s;
  } else if (t < 192 + 384 + 768) {
    int u = t - 576;
    const float* r = w3 + u * 1152;
    float s = 0.f;
    for (int i = 0; i < 1152; i++) s += r[i] * r[i];
    s3[u] = s;
  }
}

// ---------------- transpose conv weights (layer1 only) ---------------------
__global__ __launch_bounds__(256) void tr_w_kernel(
    const float* __restrict__ in, float* __restrict__ out, int O, int K) {
  int idx = blockIdx.x * blockDim.x + threadIdx.x;
  int total = 3 * O * K;
  if (idx >= total) return;
  int o = idx % O;
  int r = idx / O;
  int k = r % K;
  int br = r / K;
  out[((size_t)br * K + k) * O + o] = in[((size_t)br * O + o) * K + k];
}

// ---------------- transpose fc_w: [oo][br][c][pth] -> [oo][br][pth][c] -----
__global__ __launch_bounds__(256) void tr_fcw_kernel(
    const float* __restrict__ fcw, float* __restrict__ fcwt) {
  int tb = blockIdx.x;  // 18 pth-tiles x 8 c-tiles
  int pt = tb % 18, ct = tb / 18;
  int ob = blockIdx.y;  // oo*3+br
  __shared__ float tile[32][33];
  const float* src = fcw + (size_t)ob * 147456;
  float* dst = fcwt + (size_t)ob * 147456;
  int tx = threadIdx.x, ty = threadIdx.y;  // (32,8)
  int pth0 = pt * 32, c0 = ct * 32;
  for (int i = 0; i < 32; i += 8) {
    int c = c0 + ty + i;
    tile[ty + i][tx] = src[(size_t)c * 576 + pth0 + tx];
  }
  __syncthreads();
  for (int i = 0; i < 32; i += 8) {
    int pth = pth0 + ty + i;
    dst[(size_t)pth * 256 + c0 + tx] = tile[tx][ty + i];
  }
}

// ---------------- pack weights into MFMA-fragment layout, split hi/lo ------
template <int CIN, int COUT>
__global__ __launch_bounds__(256) void pack_w_kernel(
    const float* __restrict__ w, unsigned short* __restrict__ bph,
    unsigned short* __restrict__ bpl) {
  constexpr int K = CIN * 9;
  constexpr int CC = CIN / 32;
  const int n = blockIdx.x, br = blockIdx.z;
  const int t = threadIdx.x;
  __shared__ float row[K];
  const float* src = w + ((size_t)br * COUT + n) * K;
  for (int i = t; i < K; i += 256) row[i] = src[i];
  __syncthreads();
  for (int i = t; i < K; i += 256) {
    int kpos = i / CIN;
    int e = i - kpos * CIN;  // = c
    float f = row[e * 9 + kpos];
    __hip_bfloat16 h = __float2bfloat16(f);
    float hf = __bfloat162float(h);
    __hip_bfloat16 l = __float2bfloat16(f - hf);
    size_t oidx =
        (((size_t)br * 9 * CC + (size_t)kpos * CC + (e >> 5)) * COUT + n) * 32 +
        (e & 31);
    bph[oidx] = *reinterpret_cast<unsigned short*>(&h);
    bpl[oidx] = *reinterpret_cast<unsigned short*>(&l);
  }
}

// ---------------- Layer 1: 1ch 5x5 pad2 -> 64ch, crelu(rank31), pool -------
// 256 threads = 4 waves; block covers 8x8 conv pixels (4x4 pool outputs).
// Threshold: cheap w-path (thr>=w iff #{d>=w}>=32 -> min(thr,w)=w, one
// ballot) with rare exact radix-select fallback.
__global__ __launch_bounds__(256) void layer1_kernel(
    const float* __restrict__ x,    // [16][3][96][96]
    const float* __restrict__ w1t,  // [3][25][64]
    const float* __restrict__ sw2v, // [3][64]
    const float* __restrict__ tri,  // [3][3]
    float* __restrict__ a1)         // [3][16][48][48][64]
{
  const int gidx = blockIdx.x;  // 12 x 12 tiles
  const int gy = gidx / 12, gx = gidx % 12;
  const int n = blockIdx.y, br = blockIdx.z;
  const int t = threadIdx.x;
  const int lane = t & 63, wid = t >> 6;

  __shared__ __align__(16) float win[12][12];
  __shared__ float sp2s[64];

  const int y0 = gy * 8 - 2, x0 = gx * 8 - 2;
  const float* xb = x + ((size_t)(n * 3 + br)) * 96 * 96;
  if (t < 144) {
    int wy = t / 12, wx = t - (t / 12) * 12;
    int y = y0 + wy, xx = x0 + wx;
    float v = 0.f;
    if (y >= 0 && y < 96 && xx >= 0 && xx < 96) v = xb[y * 96 + xx];
    win[wy][wx] = v;
  }
  __syncthreads();

  if (t < 64) {
    int py = t >> 3, px = t & 7;
    float s = 0.f;
#pragma unroll
    for (int ky = 0; ky < 5; ky++)
#pragma unroll
      for (int kx = 0; kx < 5; kx++) {
        float v = win[py + ky][px + kx];
        s += v * v;
      }
    sp2s[t] = s;
  }
  __syncthreads();

  const float* wb = w1t + br * 25 * 64 + lane;
  float wv[25];
#pragma unroll
  for (int j = 0; j < 25; j++) wv[j] = wb[j * 64];

  float acc[2][8] = {};
#pragma unroll
  for (int wyy = 0; wyy < 6; wyy++) {
    const int wy = wid * 2 + wyy;
    float4 ra = *reinterpret_cast<const float4*>(&win[wy][0]);
    float4 rb = *reinterpret_cast<const float4*>(&win[wy][4]);
    float4 rc = *reinterpret_cast<const float4*>(&win[wy][8]);
    float r[12] = {ra.x, ra.y, ra.z, ra.w, rb.x, rb.y,
                   rb.z, rb.w, rc.x, rc.y, rc.z, rc.w};
#pragma unroll
    for (int py = 0; py < 2; py++) {
      int ky = wyy - py;
      if (ky < 0 || ky > 4) continue;
#pragma unroll
      for (int kx = 0; kx < 5; kx++) {
        float wvv = wv[ky * 5 + kx];
#pragma unroll
        for (int px = 0; px < 8; px++) acc[py][px] += wvv * r[px + kx];
      }
    }
  }

  const float sw = sw2v[br * 64 + lane];
  const float w_ = tri[br * 3 + 0];

  float dv[16];
#pragma unroll
  for (int p = 0; p < 16; p++) {
    const int py = p >> 3, px = p & 7;
    float d2 = sp2s[(wid * 2 + py) * 8 + px] + sw - 2.f * acc[py][px];
    dv[p] = sqrtf(fmaxf(d2, 1e-12f));
  }

  // cheap w-path: thr>=w_ iff #{d>=w_}>=32 -> min(thr,w_)=w_ (exact)
  float thrv[16];
  unsigned int need = 0;
#pragma unroll
  for (int p = 0; p < 16; p++) {
    int cnt = __popcll(__ballot(dv[p] >= w_));
    if (cnt >= 32) thrv[p] = w_;
    else need |= (1u << p);
  }
  if (need) {  // wave-uniform, rare
    for (int p = 0; p < 16; p++) {
      if (!((need >> p) & 1)) continue;
      unsigned int key = __float_as_uint(dv[p]);
      unsigned int pre = 0;
      int rem = 31;
      for (int b = 30; b >= 0; --b) {
        unsigned int top = (pre >> b) | 1u;
        int cnt = __popcll(__ballot((key >> b) == top));
        if (cnt > rem) pre |= (1u << b);
        else rem -= cnt;
      }
      thrv[p] = __uint_as_float(pre);
    }
  }

  const float A2[2][2] = {{0.9f, 0.93f}, {0.96f, 0.99f}};
  float pooled[4] = {0.f, 0.f, 0.f, 0.f};
#pragma unroll
  for (int p = 0; p < 16; p++) {
    const int py = p >> 3, px = p & 7;
    float th = fminf(thrv[p], w_);
    float a = 1.f - ((dv[p] > th) ? w_ : dv[p]) / w_;
    pooled[px >> 1] += a * A2[py][px & 1];
  }
#pragma unroll
  for (int g = 0; g < 4; g++) {
    a1[((((size_t)(br * 16 + n)) * 48 + (gy * 4 + wid)) * 48 + (gx * 4 + g)) *
           64 + lane] = pooled[g] * 0.25f;
  }
}

// ---------------- Layers 2/3: MFMA split-bf16 RBF conv ---------------------
// 256 threads = 4 waves; block covers 4 rows x 8 cols of conv pixels.
// Zero-window fast path: if the whole input window is exactly 0, every pixel
// has d[col]=sqrt(|w_col|^2): skip conv, one select for the whole block.
template <int CIN, int COUT, int HIN, int KRANK, int POOL, int LIDX>
__global__ __launch_bounds__(256) void mfma_rbf3(
    const float* __restrict__ in,            // [3][16][HIN][HIN][CIN]
    const unsigned short* __restrict__ bph,  // packed hi
    const unsigned short* __restrict__ bpl,  // packed lo
    const float* __restrict__ sw2v,          // [3][COUT]
    const float* __restrict__ tri,
    float* __restrict__ out) {
  constexpr int CC = CIN / 32;
  constexpr int NCH = 9 * CC;               // K chunks of 32
  constexpr int NT = COUT / 16;
  constexpr int NTW = NT / 4;               // N tiles per wave
  constexpr int PADC = COUT + 4;
  constexpr int WIN_USH = 60 * CIN;         // per buffer (h or l)
  constexpr int WIN_BYTES = 2 * WIN_USH * 2;
  constexpr int DMAT_BYTES = 32 * PADC * 4;
  constexpr int UNI_BYTES = WIN_BYTES > DMAT_BYTES ? WIN_BYTES : DMAT_BYTES;

  __shared__ __align__(16) char uni[UNI_BYTES];
  __shared__ float cellq[60][4];
  __shared__ float cellsum[60];
  __shared__ float sp2[32];
  __shared__ float thrs[32];
  __shared__ float sw2s[COUT];
  __shared__ int zflag;

  unsigned short* winh = (unsigned short*)uni;
  unsigned short* winl = winh + WIN_USH;
  float* dmat = (float*)uni;  // aliases win after conv

  const int GX = HIN / 8;
  const int gy = blockIdx.x / GX, gx = blockIdx.x % GX;
  const int n = blockIdx.y, br = blockIdx.z;
  const int t = threadIdx.x;
  const int lane = t & 63;
  const int wvid = t >> 6;
  const int ng = wvid;  // N quarter

  const float w_ = tri[br * 3 + LIDX];
  const int y0 = gy * 4 - 1, x0 = gx * 8 - 1;
  const float* ib = in + ((size_t)(br * 16 + n)) * HIN * HIN * CIN;

  // ---- stage window (fp32 -> bf16 hi/lo, swizzled) + cell partial sums ----
  for (int i = t; i < COUT; i += 256) sw2s[i] = sw2v[br * COUT + i];
  if (t < 240) {
    const int cell = t >> 2, q = t & 3;
    const int wy = cell / 10, wx = cell - (cell / 10) * 10;
    const int y = y0 + wy, xx = x0 + wx;
    const bool ok = (y >= 0 && y < HIN && xx >= 0 && xx < HIN);
    const float* rp = ib + ((size_t)y * HIN + xx) * CIN + q * (CIN / 4);
    const int sx = (wx & 7) << 3;
    float ss = 0.f;
#pragma unroll
    for (int cq = 0; cq < CIN / 16; cq++) {
      float4 v = ok ? *reinterpret_cast<const float4*>(rp + cq * 4)
                    : make_float4(0.f, 0.f, 0.f, 0.f);
      unsigned short hh[4], ll[4];
      float fv[4] = {v.x, v.y, v.z, v.w};
#pragma unroll
      for (int j = 0; j < 4; j++) {
        float f = fv[j];
        ss += f * f;
        __hip_bfloat16 h = __float2bfloat16(f);
        float hf = __bfloat162float(h);
        __hip_bfloat16 l = __float2bfloat16(f - hf);
        hh[j] = *reinterpret_cast<unsigned short*>(&h);
        ll[j] = *reinterpret_cast<unsigned short*>(&l);
      }
      int c = q * (CIN / 4) + cq * 4;
      int cst = c ^ sx;
      *reinterpret_cast<ushort4*>(&winh[cell * CIN + cst]) =
          make_ushort4(hh[0], hh[1], hh[2], hh[3]);
      *reinterpret_cast<ushort4*>(&winl[cell * CIN + cst]) =
          make_ushort4(ll[0], ll[1], ll[2], ll[3]);
    }
    cellq[cell][q] = ss;
  }
  __syncthreads();
  if (t < 60)
    cellsum[t] = cellq[t][0] + cellq[t][1] + cellq[t][2] + cellq[t][3];
  __syncthreads();
  if (t < 32) {
    int py = t >> 3, px = t & 7;
    float s = 0.f;
#pragma unroll
    for (int ky = 0; ky < 3; ky++)
#pragma unroll
      for (int kx = 0; kx < 3; kx++) s += cellsum[(py + ky) * 10 + px + kx];
    sp2[t] = s;
  }
  if (t == 0) {
    float s = 0.f;
    for (int i = 0; i < 60; i++) s += cellsum[i];
    zflag = (s == 0.f);
  }
  __syncthreads();

  // ---- zero-window fast path ---------------------------------------------
  if (zflag) {
    for (int col = t; col < COUT; col += 256)
      dmat[col] = sqrtf(fmaxf(sw2s[col], 1e-12f));
    __syncthreads();
    if (wvid == 0) {
      float v0, v1, v2, v3;
      if constexpr (COUT == 256) {
        float4 f = *reinterpret_cast<const float4*>(&dmat[lane * 4]);
        v0 = f.x; v1 = f.y; v2 = f.z; v3 = f.w;
      } else {
        float2 f = *reinterpret_cast<const float2*>(&dmat[lane * 2]);
        v0 = f.x; v1 = f.y; v2 = 0.f; v3 = 0.f;
      }
      int cnt = __popcll(__ballot(v0 >= w_)) + __popcll(__ballot(v1 >= w_));
      if constexpr (COUT == 256)
        cnt += __popcll(__ballot(v2 >= w_)) + __popcll(__ballot(v3 >= w_));
      float thr;
      if (cnt > KRANK) {
        thr = w_;
      } else {
        unsigned int k0 = __float_as_uint(v0), k1 = __float_as_uint(v1);
        unsigned int k2 = __float_as_uint(v2), k3 = __float_as_uint(v3);
        unsigned int pre = 0;
        int rem = KRANK;
        for (int b = 30; b >= 0; --b) {
          unsigned int top = (pre >> b) | 1u;
          int c = __popcll(__ballot((k0 >> b) == top)) +
                  __popcll(__ballot((k1 >> b) == top));
          if constexpr (COUT == 256)
            c += __popcll(__ballot((k2 >> b) == top)) +
                 __popcll(__ballot((k3 >> b) == top));
          if (c > rem) pre |= (1u << b);
          else rem -= c;
        }
        thr = __uint_as_float(pre);
      }
      if (lane == 0) thrs[0] = thr;
    }
    __syncthreads();
    const float th = fminf(thrs[0], w_);
    if (POOL) {
      const int GW = HIN / 2;
      float* ob = out + ((size_t)(br * 16 + n)) * GW * GW * COUT;
      for (int col = t; col < COUT; col += 256) {
        float d0 = dmat[col];
        float a = 1.f - ((d0 > th) ? w_ : d0) / w_;
        float po = 0.25f * (a * 0.9f + a * 0.93f + a * 0.96f + a * 0.99f);
#pragma unroll
        for (int q = 0; q < 8; q++) {
          int qy = q >> 2, qx = q & 3;
          ob[((size_t)((gy * 2 + qy) * GW + gx * 4 + qx)) * COUT + col] = po;
        }
      }
    } else {
      float* ob = out + ((size_t)(br * 16 + n)) * HIN * HIN * COUT;
      for (int col = t; col < COUT; col += 256) {
        float d0 = dmat[col];
        float a = 1.f - ((d0 > th) ? w_ : d0) / w_;
        for (int r = 0; r < 32; r++) {
          int oy = gy * 4 + (r >> 3), ox = gx * 8 + (r & 7);
          ob[((size_t)(oy * HIN + ox)) * COUT + col] = a;
        }
      }
    }
    return;
  }

  // ---- conv: D[pixel][filter], 3-term split bf16, reg-dbuf B pipeline ----
  const int pix0 = lane & 15;
  const int g8 = (lane >> 4) << 3;
  const int ppy = pix0 >> 3, ppx = pix0 & 7;

  f32x4 acc[2][NTW];
  f32x4 zz = {0.f, 0.f, 0.f, 0.f};
#pragma unroll
  for (int mt = 0; mt < 2; mt++)
#pragma unroll
    for (int nt = 0; nt < NTW; nt++) acc[mt][nt] = zz;

  const size_t bbase = (size_t)br * NCH;
  const int nb0 = ng * (NTW * 16) + pix0;

  bf16x8 bufA[2 * NTW], bufB[2 * NTW];

  auto loadB = [&](int chunk, bf16x8* dst) {
    const unsigned short* p0 =
        bph + ((bbase + chunk) * COUT + nb0) * 32 + g8;
    const unsigned short* p1 =
        bpl + ((bbase + chunk) * COUT + nb0) * 32 + g8;
#pragma unroll
    for (int nt = 0; nt < NTW; nt++) {
      dst[2 * nt] = *reinterpret_cast<const bf16x8*>(p0 + nt * 512);
      dst[2 * nt + 1] = *reinterpret_cast<const bf16x8*>(p1 + nt * 512);
    }
  };

  auto compute = [&](int chunk, bf16x8* b) {
    const int kpos = chunk / CC, cc = chunk - (chunk / CC) * CC;
    const int ky = kpos / 3, kx = kpos - (kpos / 3) * 3;
    const int wx = ppx + kx;
    const int sx = (wx & 7) << 3;
    const int cbase = ((cc << 5) + g8) ^ sx;
#pragma unroll
    for (int mt = 0; mt < 2; mt++) {
      const int r0 = (mt * 2 + ppy + ky) * 10 + wx;
      bf16x8 ah = *reinterpret_cast<const bf16x8*>(&winh[r0 * CIN + cbase]);
      bf16x8 al = *reinterpret_cast<const bf16x8*>(&winl[r0 * CIN + cbase]);
#pragma unroll
      for (int nt = 0; nt < NTW; nt++) {
        acc[mt][nt] = __builtin_amdgcn_mfma_f32_16x16x32_bf16(
            ah, b[2 * nt], acc[mt][nt], 0, 0, 0);
        acc[mt][nt] = __builtin_amdgcn_mfma_f32_16x16x32_bf16(
            ah, b[2 * nt + 1], acc[mt][nt], 0, 0, 0);
        acc[mt][nt] = __builtin_amdgcn_mfma_f32_16x16x32_bf16(
            al, b[2 * nt], acc[mt][nt], 0, 0, 0);
      }
    }
  };

  loadB(0, bufA);
  for (int ch = 0; ch < NCH; ch += 2) {
    loadB(ch + 1, bufB);
    compute(ch, bufA);
    if (ch + 2 < NCH) loadB(ch + 2, bufA);
    compute(ch + 1, bufB);
  }

  __syncthreads();  // conv reads of win done (alias!), sp2 visible

  // ---- d = sqrt(|p|^2 + |w|^2 - 2 dot) into dmat -------------------------
  const int rgrp = (lane >> 4) << 2;
#pragma unroll
  for (int mt = 0; mt < 2; mt++) {
    const int prow = mt * 16 + rgrp;
#pragma unroll
    for (int nt = 0; nt < NTW; nt++) {
      const int col = ng * (NTW * 16) + nt * 16 + pix0;
      const float sw = sw2s[col];
#pragma unroll
      for (int rg = 0; rg < 4; rg++) {
        const int pix = prow + rg;
        float d2 = sp2[pix] + sw - 2.f * acc[mt][nt][rg];
        dmat[pix * PADC + col] = sqrtf(fmaxf(d2, 1e-12f));
      }
    }
  }
  __syncthreads();

  // ---- per-pixel threshold: cheap w-path, rare exact radix ---------------
  for (int i = 0; i < 8; i++) {
    const int p = wvid * 8 + i;
    float v0, v1, v2, v3;
    if constexpr (COUT == 256) {
      float4 f = *reinterpret_cast<const float4*>(&dmat[p * PADC + lane * 4]);
      v0 = f.x; v1 = f.y; v2 = f.z; v3 = f.w;
    } else {
      float2 f = *reinterpret_cast<const float2*>(&dmat[p * PADC + lane * 2]);
      v0 = f.x; v1 = f.y; v2 = 0.f; v3 = 0.f;
    }
    int cnt = __popcll(__ballot(v0 >= w_)) + __popcll(__ballot(v1 >= w_));
    if constexpr (COUT == 256)
      cnt += __popcll(__ballot(v2 >= w_)) + __popcll(__ballot(v3 >= w_));
    if (cnt > KRANK) {
      if (lane == 0) thrs[p] = w_;
      continue;
    }
    unsigned int k0 = __float_as_uint(v0), k1 = __float_as_uint(v1);
    unsigned int k2 = __float_as_uint(v2), k3 = __float_as_uint(v3);
    unsigned int pre = 0;
    int rem = KRANK;
    for (int b = 30; b >= 0; --b) {
      unsigned int top = (pre >> b) | 1u;
      int c = __popcll(__ballot((k0 >> b) == top)) +
              __popcll(__ballot((k1 >> b) == top));
      if constexpr (COUT == 256)
        c += __popcll(__ballot((k2 >> b) == top)) +
             __popcll(__ballot((k3 >> b) == top));
      if (c > rem) pre |= (1u << b);
      else rem -= c;
    }
    if (lane == 0) thrs[p] = __uint_as_float(pre);
  }
  __syncthreads();

  // ---- activation (+ pool) + store ---------------------------------------
  if (POOL) {
    const int GW = HIN / 2;
    float* ob = out + ((size_t)(br * 16 + n)) * GW * GW * COUT;
    for (int i = t; i < 8 * COUT; i += 256) {
      int q = i / COUT;
      int ch = i - q * COUT;
      int qy = q >> 2, qx = q & 3;
      int p00 = qy * 16 + qx * 2;
      float d00 = dmat[p00 * PADC + ch];
      float d01 = dmat[(p00 + 1) * PADC + ch];
      float d10 = dmat[(p00 + 8) * PADC + ch];
      float d11 = dmat[(p00 + 9) * PADC + ch];
      float t00 = fminf(thrs[p00], w_);
      float t01 = fminf(thrs[p00 + 1], w_);
      float t10 = fminf(thrs[p00 + 8], w_);
      float t11 = fminf(thrs[p00 + 9], w_);
      float a00 = 1.f - ((d00 > t00) ? w_ : d00) / w_;
      float a01 = 1.f - ((d01 > t01) ? w_ : d01) / w_;
      float a10 = 1.f - ((d10 > t10) ? w_ : d10) / w_;
      float a11 = 1.f - ((d11 > t11) ? w_ : d11) / w_;
      float po =
          0.25f * (a00 * 0.9f + a01 * 0.93f + a10 * 0.96f + a11 * 0.99f);
      ob[((size_t)((gy * 2 + qy) * GW + gx * 4 + qx)) * COUT + ch] = po;
    }
  } else {
    float* ob = out + ((size_t)(br * 16 + n)) * HIN * HIN * COUT;
    for (int i = 0; i < 8; i++) {
      int r = wvid * 8 + i;
      float4 dv = *reinterpret_cast<const float4*>(&dmat[r * PADC + lane * 4]);
      float th = fminf(thrs[r], w_);
      float4 av;
      av.x = 1.f - ((dv.x > th) ? w_ : dv.x) / w_;
      av.y = 1.f - ((dv.y > th) ? w_ : dv.y) / w_;
      av.z = 1.f - ((dv.z > th) ? w_ : dv.z) / w_;
      av.w = 1.f - ((dv.w > th) ? w_ : dv.w) / w_;
      int oy = gy * 4 + (r >> 3), ox = gx * 8 + (r & 7);
      *reinterpret_cast<float4*>(
          &ob[((size_t)(oy * HIN + ox)) * COUT + lane * 4]) = av;
    }
  }
}

// ---------------- FC: split-K partials + reduce ----------------------------
__global__ __launch_bounds__(256) void fc_partial_kernel(
    const float* __restrict__ feats, const float* __restrict__ fcwt,
    float* __restrict__ partial) {
  const int oo = blockIdx.x;  // 0..9
  const int n = blockIdx.y;   // 0..15
  const int s = blockIdx.z;   // 0..7
  const int t = threadIdx.x;
  const int i0 = s * 4608;
  float acc = 0.f;
  for (int br = 0; br < 3; br++) {
    const float4* fb = reinterpret_cast<const float4*>(
        feats + ((size_t)(br * 16 + n)) * 147456);
    const float4* wb = reinterpret_cast<const float4*>(
        fcwt + ((size_t)(oo * 3 + br)) * 147456);
    for (int i = i0 + t; i < i0 + 4608; i += 256) {
      float4 f = fb[i], w = wb[i];
      acc += f.x * w.x + f.y * w.y + f.z * w.z + f.w * w.w;
    }
  }
  __shared__ float red[256];
  red[t] = acc;
  __syncthreads();
  for (int st = 128; st > 0; st >>= 1) {
    if (t < st) red[t] += red[t + st];
    __syncthreads();
  }
  if (t == 0) partial[((size_t)oo * 16 + n) * 8 + s] = red[0];
}

__global__ __launch_bounds__(256) void fc_final_kernel(
    const float* __restrict__ partial, const float* __restrict__ fcb,
    float* __restrict__ outp) {
  const int t = threadIdx.x;
  if (t < 160) {
    int oo = t / 16, n = t % 16;
    float s = 0.f;
#pragma unroll
    for (int q = 0; q < 8; q++) s += partial[((size_t)oo * 16 + n) * 8 + q];
    outp[n * 10 + oo] = s + fcb[oo];
  }
}

// ---------------------------------------------------------------------------
extern "C" void kernel_launch(void* const* d_in, const int* in_sizes, int n_in,
                              void* d_out, int out_size, void* d_ws,
                              size_t ws_size, hipStream_t stream) {
  const float* x   = (const float*)d_in[0];
  const float* w1  = (const float*)d_in[1];
  const float* w2  = (const float*)d_in[2];
  const float* w3  = (const float*)d_in[3];
  const float* tri = (const float*)d_in[4];
  const float* fcw = (const float*)d_in[5];
  const float* fcb = (const float*)d_in[6];
  float* out = (float*)d_out;

  float* ws = (float*)d_ws;
  float* a1    = ws;                  // 7,077,888
  float* a2    = a1 + 7077888;        // 3,538,944
  float* feats = a2 + 3538944;        // 7,077,888
  float* s1    = feats + 7077888;     // 192
  float* s2    = s1 + 192;            // 384
  float* s3    = s2 + 384;            // 768
  float* w1t   = s3 + 768;            // 4,800
  unsigned short* bph2 = (unsigned short*)(w1t + 4800);  // 221,184 ushorts
  unsigned short* bpl2 = bph2 + 221184;
  unsigned short* bph3 = bpl2 + 221184;                  // 884,736
  unsigned short* bpl3 = bph3 + 884736;
  float* partial = (float*)(bpl3 + 884736);              // 1,280 floats
  float* fcwt = a1;  // aliases a1 (dead after layer2)

  tr_w_kernel<<<dim3(19), dim3(256), 0, stream>>>(w1, w1t, 64, 25);
  sw2_kernel<<<dim3(6), dim3(256), 0, stream>>>(w1, w2, w3, s1, s2, s3);
  pack_w_kernel<64, 128><<<dim3(128, 1, 3), dim3(256), 0, stream>>>(w2, bph2,
                                                                    bpl2);
  pack_w_kernel<128, 256><<<dim3(256, 1, 3), dim3(256), 0, stream>>>(w3, bph3,
                                                                     bpl3);

  layer1_kernel<<<dim3(144, 16, 3), dim3(256), 0, stream>>>(x, w1t, s1, tri,
                                                            a1);
  mfma_rbf3<64, 128, 48, 63, 1, 1>
      <<<dim3(72, 16, 3), dim3(256), 0, stream>>>(a1, bph2, bpl2, s2, tri, a2);
  // a1 dead; reuse for transposed fc weights
  tr_fcw_kernel<<<dim3(144, 30), dim3(32, 8), 0, stream>>>(fcw, fcwt);
  mfma_rbf3<128, 256, 24, 152, 0, 2>
      <<<dim3(18, 16, 3), dim3(256), 0, stream>>>(a2, bph3, bpl3, s3, tri,
                                                  feats);
  fc_partial_kernel<<<dim3(10, 16, 8), dim3(256), 0, stream>>>(feats, fcwt,
                                                               partial);
  fc_final_kernel<<<dim3(1), dim3(256), 0, stream>>>(partial, fcb, out);
}

// Round 9
// 150.379 us; speedup vs baseline: 3.5991x; 1.2902x over previous
//
#include <hip/hip_runtime.h>
#include <hip/hip_bf16.h>
#include <math.h>

typedef __attribute__((ext_vector_type(8))) short bf16x8;
typedef __attribute__((ext_vector_type(4))) float f32x4;

__device__ __forceinline__ void bsplit(float f, unsigned short& h,
                                       unsigned short& l) {
  __hip_bfloat16 hb = __float2bfloat16(f);
  float hf = __bfloat162float(hb);
  __hip_bfloat16 lb = __float2bfloat16(f - hf);
  h = *reinterpret_cast<unsigned short*>(&hb);
  l = *reinterpret_cast<unsigned short*>(&lb);
}

// ---------------- |w|^2 per filter row ----------------
__global__ __launch_bounds__(256) void sw2_kernel(
    const float* __restrict__ w1, const float* __restrict__ w2,
    const float* __restrict__ w3,
    float* __restrict__ s1, float* __restrict__ s2, float* __restrict__ s3) {
  int t = blockIdx.x * blockDim.x + threadIdx.x;
  if (t < 192) {
    const float* r = w1 + t * 25;
    float s = 0.f;
    for (int i = 0; i < 25; i++) s += r[i] * r[i];
    s1[t] = s;
  } else if (t < 192 + 384) {
    int u = t - 192;
    const float* r = w2 + u * 576;
    float s = 0.f;
    for (int i = 0; i < 576; i++) s += r[i] * r[i];
    s2[u] = s;
  } else if (t < 192 + 384 + 768) {
    int u = t - 576;
    const float* r = w3 + u * 1152;
    float s = 0.f;
    for (int i = 0; i < 1152; i++) s += r[i] * r[i];
    s3[u] = s;
  }
}

// ---------------- pack w1 into B-fragment layout [br][col(64)][k(32)] ------
__global__ __launch_bounds__(256) void pack_w1_kernel(
    const float* __restrict__ w1, unsigned short* __restrict__ bh,
    unsigned short* __restrict__ bl) {
  int idx = blockIdx.x * 256 + threadIdx.x;  // 3*64*32 = 6144
  if (idx >= 6144) return;
  int k = idx & 31;
  int col = (idx >> 5) & 63;
  int br = idx >> 11;
  float f = (k < 25) ? w1[(br * 64 + col) * 25 + k] : 0.f;
  unsigned short h, l;
  bsplit(f, h, l);
  bh[idx] = h;
  bl[idx] = l;
}

// ---------------- pack conv weights (layers 2/3), split hi/lo --------------
template <int CIN, int COUT>
__global__ __launch_bounds__(256) void pack_w_kernel(
    const float* __restrict__ w, unsigned short* __restrict__ bph,
    unsigned short* __restrict__ bpl) {
  constexpr int K = CIN * 9;
  constexpr int CC = CIN / 32;
  const int n = blockIdx.x, br = blockIdx.z;
  const int t = threadIdx.x;
  __shared__ float row[K];
  const float* src = w + ((size_t)br * COUT + n) * K;
  for (int i = t; i < K; i += 256) row[i] = src[i];
  __syncthreads();
  for (int i = t; i < K; i += 256) {
    int kpos = i / CIN;
    int e = i - kpos * CIN;  // = c
    float f = row[e * 9 + kpos];
    unsigned short h, l;
    bsplit(f, h, l);
    size_t oidx =
        (((size_t)br * 9 * CC + (size_t)kpos * CC + (e >> 5)) * COUT + n) * 32 +
        (e & 31);
    bph[oidx] = h;
    bpl[oidx] = l;
  }
}

// ---------------- Layer 1: MFMA split-bf16 5x5 conv, crelu(31), pool -------
// 256 thr = 4 waves; block = 8x8 conv pixels. Wave m owns pixel M-tile m
// (2 conv rows) and all 64 channels; pool row m.
__global__ __launch_bounds__(256) void layer1_kernel(
    const float* __restrict__ x,             // [16][3][96][96]
    const unsigned short* __restrict__ bw1h, // [3][64][32]
    const unsigned short* __restrict__ bw1l,
    const float* __restrict__ sw2v,          // [3][64]
    const float* __restrict__ tri,
    float* __restrict__ a1)                  // [3][16][48][48][64]
{
  const int gidx = blockIdx.x;  // 12 x 12 tiles
  const int gy = gidx / 12, gx = gidx % 12;
  const int n = blockIdx.y, br = blockIdx.z;
  const int t = threadIdx.x;
  const int lane = t & 63, wid = t >> 6;

  __shared__ __align__(16) float win[12][12];
  __shared__ float sp2s[64];
  __shared__ float sw2s[64];
  __shared__ __align__(16) float dmat[64][68];

  const int y0 = gy * 8 - 2, x0 = gx * 8 - 2;
  const float* xb = x + ((size_t)(n * 3 + br)) * 96 * 96;
  if (t < 144) {
    int wy = t / 12, wx = t - (t / 12) * 12;
    int y = y0 + wy, xx = x0 + wx;
    float v = 0.f;
    if (y >= 0 && y < 96 && xx >= 0 && xx < 96) v = xb[y * 96 + xx];
    win[wy][wx] = v;
  }
  if (t >= 192) sw2s[t - 192] = sw2v[br * 64 + (t - 192)];
  __syncthreads();

  if (t < 64) {
    int py = t >> 3, px = t & 7;
    float s = 0.f;
#pragma unroll
    for (int ky = 0; ky < 5; ky++)
#pragma unroll
      for (int kx = 0; kx < 5; kx++) {
        float v = win[py + ky][px + kx];
        s += v * v;
      }
    sp2s[t] = s;
  }

  // ---- A fragment: patch row = pixel (lane&15), k-slot = lane>>4 ----
  const int mrow = lane & 15;
  const int slot = lane >> 4;
  const int pixel = wid * 16 + mrow;
  const int ppy = pixel >> 3, ppx = pixel & 7;
  unsigned short ahv[8], alv[8];
#pragma unroll
  for (int j = 0; j < 8; j++) {
    int k = slot * 8 + j;
    float v = 0.f;
    if (k < 25) {
      int ky = (k * 205) >> 10;  // k/5 exact for k<32
      int kx = k - ky * 5;
      v = win[ppy + ky][ppx + kx];
    }
    bsplit(v, ahv[j], alv[j]);
  }
  bf16x8 ah = *reinterpret_cast<bf16x8*>(ahv);
  bf16x8 al = *reinterpret_cast<bf16x8*>(alv);

  // ---- B fragments (4 N-tiles of 16 ch) + 12 MFMAs ----
  f32x4 acc[4];
  f32x4 zz = {0.f, 0.f, 0.f, 0.f};
#pragma unroll
  for (int nt = 0; nt < 4; nt++) acc[nt] = zz;
#pragma unroll
  for (int nt = 0; nt < 4; nt++) {
    const int off = ((br * 64 + nt * 16 + mrow) << 5) + (slot << 3);
    bf16x8 bh = *reinterpret_cast<const bf16x8*>(bw1h + off);
    bf16x8 bl = *reinterpret_cast<const bf16x8*>(bw1l + off);
    acc[nt] = __builtin_amdgcn_mfma_f32_16x16x32_bf16(ah, bh, acc[nt], 0, 0, 0);
    acc[nt] = __builtin_amdgcn_mfma_f32_16x16x32_bf16(ah, bl, acc[nt], 0, 0, 0);
    acc[nt] = __builtin_amdgcn_mfma_f32_16x16x32_bf16(al, bh, acc[nt], 0, 0, 0);
  }
  __syncthreads();  // sp2s ready

  // ---- d matrix ----
  const float w_ = tri[br * 3 + 0];
  const int rgrp = slot * 4;
#pragma unroll
  for (int nt = 0; nt < 4; nt++) {
    const int ch = nt * 16 + mrow;
    const float sw = sw2s[ch];
#pragma unroll
    for (int rg = 0; rg < 4; rg++) {
      const int p = wid * 16 + rgrp + rg;
      float d2 = sp2s[p] + sw - 2.f * acc[nt][rg];
      dmat[p][ch] = sqrtf(fmaxf(d2, 1e-12f));
    }
  }
  // wave-local from here: each wave reads only its own 16 dmat rows

  // ---- per-pixel threshold: cheap w-path + rare radix fallback ----
  float thrv[16];
  unsigned int need = 0;
#pragma unroll
  for (int i = 0; i < 16; i++) {
    float v = dmat[wid * 16 + i][lane];
    int cnt = __popcll(__ballot(v >= w_));
    if (cnt >= 32) thrv[i] = w_;
    else need |= (1u << i);
  }
  if (need) {
#pragma unroll
    for (int i = 0; i < 16; i++) {
      if (!((need >> i) & 1)) continue;
      unsigned int key = __float_as_uint(dmat[wid * 16 + i][lane]);
      unsigned int pre = 0;
      int rem = 31;
      for (int b = 30; b >= 0; --b) {
        unsigned int top = (pre >> b) | 1u;
        int cnt = __popcll(__ballot((key >> b) == top));
        if (cnt > rem) pre |= (1u << b);
        else rem -= cnt;
      }
      thrv[i] = __uint_as_float(pre);
    }
  }

  // ---- pool (wave wid = pool row wid), lane = channel ----
  const float A2[2][2] = {{0.9f, 0.93f}, {0.96f, 0.99f}};
#pragma unroll
  for (int g = 0; g < 4; g++) {
    float pooled = 0.f;
#pragma unroll
    for (int py = 0; py < 2; py++)
#pragma unroll
      for (int q = 0; q < 2; q++) {
        int pi = py * 8 + g * 2 + q;
        float d = dmat[wid * 16 + pi][lane];
        float th = fminf(thrv[pi], w_);
        float a = 1.f - ((d > th) ? w_ : d) / w_;
        pooled += a * A2[py][q];
      }
    a1[((((size_t)(br * 16 + n)) * 48 + (gy * 4 + wid)) * 48 + (gx * 4 + g)) *
           64 + lane] = pooled * 0.25f;
  }
}

// ---------------- Layers 2/3: MFMA split-bf16 RBF conv ---------------------
// POOL=1 -> out [3][16][GW][GW][COUT] (a2). POOL=0 -> TRANSPOSED feats
// [3][16][COUT][576] to match fc_w's native order.
template <int CIN, int COUT, int HIN, int KRANK, int POOL, int LIDX>
__global__ __launch_bounds__(256) void mfma_rbf3(
    const float* __restrict__ in,            // [3][16][HIN][HIN][CIN]
    const unsigned short* __restrict__ bph,  // packed hi
    const unsigned short* __restrict__ bpl,  // packed lo
    const float* __restrict__ sw2v,          // [3][COUT]
    const float* __restrict__ tri,
    float* __restrict__ out) {
  constexpr int CC = CIN / 32;
  constexpr int NCH = 9 * CC;
  constexpr int NT = COUT / 16;
  constexpr int NTW = NT / 4;
  constexpr int PADC = COUT + 4;
  constexpr int WIN_USH = 60 * CIN;
  constexpr int WIN_BYTES = 2 * WIN_USH * 2;
  constexpr int DMAT_BYTES = 32 * PADC * 4;
  constexpr int UNI_BYTES = WIN_BYTES > DMAT_BYTES ? WIN_BYTES : DMAT_BYTES;

  __shared__ __align__(16) char uni[UNI_BYTES];
  __shared__ float cellq[60][4];
  __shared__ float cellsum[60];
  __shared__ float sp2[32];
  __shared__ float thrs[32];
  __shared__ float sw2s[COUT];
  __shared__ int zflag;

  unsigned short* winh = (unsigned short*)uni;
  unsigned short* winl = winh + WIN_USH;
  float* dmat = (float*)uni;

  const int GX = HIN / 8;
  const int gy = blockIdx.x / GX, gx = blockIdx.x % GX;
  const int n = blockIdx.y, br = blockIdx.z;
  const int t = threadIdx.x;
  const int lane = t & 63;
  const int wvid = t >> 6;
  const int ng = wvid;

  const float w_ = tri[br * 3 + LIDX];
  const int y0 = gy * 4 - 1, x0 = gx * 8 - 1;
  const float* ib = in + ((size_t)(br * 16 + n)) * HIN * HIN * CIN;

  for (int i = t; i < COUT; i += 256) sw2s[i] = sw2v[br * COUT + i];
  if (t < 240) {
    const int cell = t >> 2, q = t & 3;
    const int wy = cell / 10, wx = cell - (cell / 10) * 10;
    const int y = y0 + wy, xx = x0 + wx;
    const bool ok = (y >= 0 && y < HIN && xx >= 0 && xx < HIN);
    const float* rp = ib + ((size_t)y * HIN + xx) * CIN + q * (CIN / 4);
    const int sx = (wx & 7) << 3;
    float ss = 0.f;
#pragma unroll
    for (int cq = 0; cq < CIN / 16; cq++) {
      float4 v = ok ? *reinterpret_cast<const float4*>(rp + cq * 4)
                    : make_float4(0.f, 0.f, 0.f, 0.f);
      unsigned short hh[4], ll[4];
      float fv[4] = {v.x, v.y, v.z, v.w};
#pragma unroll
      for (int j = 0; j < 4; j++) {
        float f = fv[j];
        ss += f * f;
        bsplit(f, hh[j], ll[j]);
      }
      int c = q * (CIN / 4) + cq * 4;
      int cst = c ^ sx;
      *reinterpret_cast<ushort4*>(&winh[cell * CIN + cst]) =
          make_ushort4(hh[0], hh[1], hh[2], hh[3]);
      *reinterpret_cast<ushort4*>(&winl[cell * CIN + cst]) =
          make_ushort4(ll[0], ll[1], ll[2], ll[3]);
    }
    cellq[cell][q] = ss;
  }
  __syncthreads();
  if (t < 60)
    cellsum[t] = cellq[t][0] + cellq[t][1] + cellq[t][2] + cellq[t][3];
  __syncthreads();
  if (t < 32) {
    int py = t >> 3, px = t & 7;
    float s = 0.f;
#pragma unroll
    for (int ky = 0; ky < 3; ky++)
#pragma unroll
      for (int kx = 0; kx < 3; kx++) s += cellsum[(py + ky) * 10 + px + kx];
    sp2[t] = s;
  }
  if (t == 0) {
    float s = 0.f;
    for (int i = 0; i < 60; i++) s += cellsum[i];
    zflag = (s == 0.f);
  }
  __syncthreads();

  // ---- zero-window fast path ---------------------------------------------
  if (zflag) {
    for (int col = t; col < COUT; col += 256)
      dmat[col] = sqrtf(fmaxf(sw2s[col], 1e-12f));
    __syncthreads();
    if (wvid == 0) {
      float v0, v1, v2, v3;
      if constexpr (COUT == 256) {
        float4 f = *reinterpret_cast<const float4*>(&dmat[lane * 4]);
        v0 = f.x; v1 = f.y; v2 = f.z; v3 = f.w;
      } else {
        float2 f = *reinterpret_cast<const float2*>(&dmat[lane * 2]);
        v0 = f.x; v1 = f.y; v2 = 0.f; v3 = 0.f;
      }
      int cnt = __popcll(__ballot(v0 >= w_)) + __popcll(__ballot(v1 >= w_));
      if constexpr (COUT == 256)
        cnt += __popcll(__ballot(v2 >= w_)) + __popcll(__ballot(v3 >= w_));
      float thr;
      if (cnt > KRANK) {
        thr = w_;
      } else {
        unsigned int k0 = __float_as_uint(v0), k1 = __float_as_uint(v1);
        unsigned int k2 = __float_as_uint(v2), k3 = __float_as_uint(v3);
        unsigned int pre = 0;
        int rem = KRANK;
        for (int b = 30; b >= 0; --b) {
          unsigned int top = (pre >> b) | 1u;
          int c = __popcll(__ballot((k0 >> b) == top)) +
                  __popcll(__ballot((k1 >> b) == top));
          if constexpr (COUT == 256)
            c += __popcll(__ballot((k2 >> b) == top)) +
                 __popcll(__ballot((k3 >> b) == top));
          if (c > rem) pre |= (1u << b);
          else rem -= c;
        }
        thr = __uint_as_float(pre);
      }
      if (lane == 0) thrs[0] = thr;
    }
    __syncthreads();
    const float th = fminf(thrs[0], w_);
    if (POOL) {
      const int GW = HIN / 2;
      float* ob = out + ((size_t)(br * 16 + n)) * GW * GW * COUT;
      for (int col = t; col < COUT; col += 256) {
        float d0 = dmat[col];
        float a = 1.f - ((d0 > th) ? w_ : d0) / w_;
        float po = 0.25f * (a * 0.9f + a * 0.93f + a * 0.96f + a * 0.99f);
#pragma unroll
        for (int q = 0; q < 8; q++) {
          int qy = q >> 2, qx = q & 3;
          ob[((size_t)((gy * 2 + qy) * GW + gx * 4 + qx)) * COUT + col] = po;
        }
      }
    } else {
      // transposed feats [col][576]
      float* ob = out + ((size_t)(br * 16 + n)) * COUT * 576;
      for (int col = t; col < COUT; col += 256) {
        float d0 = dmat[col];
        float a = 1.f - ((d0 > th) ? w_ : d0) / w_;
        float4 av = make_float4(a, a, a, a);
#pragma unroll
        for (int row = 0; row < 4; row++) {
          float* dst = ob + (size_t)col * 576 + (gy * 4 + row) * 24 + gx * 8;
          *reinterpret_cast<float4*>(dst) = av;
          *reinterpret_cast<float4*>(dst + 4) = av;
        }
      }
    }
    return;
  }

  // ---- conv: reg-dbuf B pipeline, 3-term split ---------------------------
  const int pix0 = lane & 15;
  const int g8 = (lane >> 4) << 3;
  const int ppy = pix0 >> 3, ppx = pix0 & 7;

  f32x4 acc[2][NTW];
  f32x4 zz = {0.f, 0.f, 0.f, 0.f};
#pragma unroll
  for (int mt = 0; mt < 2; mt++)
#pragma unroll
    for (int nt = 0; nt < NTW; nt++) acc[mt][nt] = zz;

  const size_t bbase = (size_t)br * NCH;
  const int nb0 = ng * (NTW * 16) + pix0;

  bf16x8 bufA[2 * NTW], bufB[2 * NTW];

  auto loadB = [&](int chunk, bf16x8* dst) {
    const unsigned short* p0 = bph + ((bbase + chunk) * COUT + nb0) * 32 + g8;
    const unsigned short* p1 = bpl + ((bbase + chunk) * COUT + nb0) * 32 + g8;
#pragma unroll
    for (int nt = 0; nt < NTW; nt++) {
      dst[2 * nt] = *reinterpret_cast<const bf16x8*>(p0 + nt * 512);
      dst[2 * nt + 1] = *reinterpret_cast<const bf16x8*>(p1 + nt * 512);
    }
  };

  auto compute = [&](int chunk, bf16x8* b) {
    const int kpos = chunk / CC, cc = chunk - (chunk / CC) * CC;
    const int ky = kpos / 3, kx = kpos - (kpos / 3) * 3;
    const int wx = ppx + kx;
    const int sx = (wx & 7) << 3;
    const int cbase = ((cc << 5) + g8) ^ sx;
#pragma unroll
    for (int mt = 0; mt < 2; mt++) {
      const int r0 = (mt * 2 + ppy + ky) * 10 + wx;
      bf16x8 ah = *reinterpret_cast<const bf16x8*>(&winh[r0 * CIN + cbase]);
      bf16x8 al = *reinterpret_cast<const bf16x8*>(&winl[r0 * CIN + cbase]);
#pragma unroll
      for (int nt = 0; nt < NTW; nt++) {
        acc[mt][nt] = __builtin_amdgcn_mfma_f32_16x16x32_bf16(
            ah, b[2 * nt], acc[mt][nt], 0, 0, 0);
        acc[mt][nt] = __builtin_amdgcn_mfma_f32_16x16x32_bf16(
            ah, b[2 * nt + 1], acc[mt][nt], 0, 0, 0);
        acc[mt][nt] = __builtin_amdgcn_mfma_f32_16x16x32_bf16(
            al, b[2 * nt], acc[mt][nt], 0, 0, 0);
      }
    }
  };

  loadB(0, bufA);
  for (int ch = 0; ch < NCH; ch += 2) {
    loadB(ch + 1, bufB);
    compute(ch, bufA);
    if (ch + 2 < NCH) loadB(ch + 2, bufA);
    compute(ch + 1, bufB);
  }

  __syncthreads();  // conv reads of win done (alias!), sp2 visible

  const int rgrp = (lane >> 4) << 2;
#pragma unroll
  for (int mt = 0; mt < 2; mt++) {
    const int prow = mt * 16 + rgrp;
#pragma unroll
    for (int nt = 0; nt < NTW; nt++) {
      const int col = ng * (NTW * 16) + nt * 16 + pix0;
      const float sw = sw2s[col];
#pragma unroll
      for (int rg = 0; rg < 4; rg++) {
        const int pix = prow + rg;
        float d2 = sp2[pix] + sw - 2.f * acc[mt][nt][rg];
        dmat[pix * PADC + col] = sqrtf(fmaxf(d2, 1e-12f));
      }
    }
  }
  __syncthreads();

  for (int i = 0; i < 8; i++) {
    const int p = wvid * 8 + i;
    float v0, v1, v2, v3;
    if constexpr (COUT == 256) {
      float4 f = *reinterpret_cast<const float4*>(&dmat[p * PADC + lane * 4]);
      v0 = f.x; v1 = f.y; v2 = f.z; v3 = f.w;
    } else {
      float2 f = *reinterpret_cast<const float2*>(&dmat[p * PADC + lane * 2]);
      v0 = f.x; v1 = f.y; v2 = 0.f; v3 = 0.f;
    }
    int cnt = __popcll(__ballot(v0 >= w_)) + __popcll(__ballot(v1 >= w_));
    if constexpr (COUT == 256)
      cnt += __popcll(__ballot(v2 >= w_)) + __popcll(__ballot(v3 >= w_));
    if (cnt > KRANK) {
      if (lane == 0) thrs[p] = w_;
      continue;
    }
    unsigned int k0 = __float_as_uint(v0), k1 = __float_as_uint(v1);
    unsigned int k2 = __float_as_uint(v2), k3 = __float_as_uint(v3);
    unsigned int pre = 0;
    int rem = KRANK;
    for (int b = 30; b >= 0; --b) {
      unsigned int top = (pre >> b) | 1u;
      int c = __popcll(__ballot((k0 >> b) == top)) +
              __popcll(__ballot((k1 >> b) == top));
      if constexpr (COUT == 256)
        c += __popcll(__ballot((k2 >> b) == top)) +
             __popcll(__ballot((k3 >> b) == top));
      if (c > rem) pre |= (1u << b);
      else rem -= c;
    }
    if (lane == 0) thrs[p] = __uint_as_float(pre);
  }
  __syncthreads();

  if (POOL) {
    const int GW = HIN / 2;
    float* ob = out + ((size_t)(br * 16 + n)) * GW * GW * COUT;
    for (int i = t; i < 8 * COUT; i += 256) {
      int q = i / COUT;
      int ch = i - q * COUT;
      int qy = q >> 2, qx = q & 3;
      int p00 = qy * 16 + qx * 2;
      float d00 = dmat[p00 * PADC + ch];
      float d01 = dmat[(p00 + 1) * PADC + ch];
      float d10 = dmat[(p00 + 8) * PADC + ch];
      float d11 = dmat[(p00 + 9) * PADC + ch];
      float t00 = fminf(thrs[p00], w_);
      float t01 = fminf(thrs[p00 + 1], w_);
      float t10 = fminf(thrs[p00 + 8], w_);
      float t11 = fminf(thrs[p00 + 9], w_);
      float a00 = 1.f - ((d00 > t00) ? w_ : d00) / w_;
      float a01 = 1.f - ((d01 > t01) ? w_ : d01) / w_;
      float a10 = 1.f - ((d10 > t10) ? w_ : d10) / w_;
      float a11 = 1.f - ((d11 > t11) ? w_ : d11) / w_;
      float po =
          0.25f * (a00 * 0.9f + a01 * 0.93f + a10 * 0.96f + a11 * 0.99f);
      ob[((size_t)((gy * 2 + qy) * GW + gx * 4 + qx)) * COUT + ch] = po;
    }
  } else {
    // transposed feats [ch][576]
    float* ob = out + ((size_t)(br * 16 + n)) * COUT * 576;
    for (int item = t; item < COUT * 4; item += 256) {
      int ch = item & (COUT - 1);
      int rowq = item >> 8;
      float vals[8];
#pragma unroll
      for (int px = 0; px < 8; px++) {
        int p = rowq * 8 + px;
        float d = dmat[p * PADC + ch];
        float tt = fminf(thrs[p], w_);
        vals[px] = 1.f - ((d > tt) ? w_ : d) / w_;
      }
      float* dst = ob + (size_t)ch * 576 + (gy * 4 + rowq) * 24 + gx * 8;
      *reinterpret_cast<float4*>(dst) =
          make_float4(vals[0], vals[1], vals[2], vals[3]);
      *reinterpret_cast<float4*>(dst + 4) =
          make_float4(vals[4], vals[5], vals[6], vals[7]);
    }
  }
}

// ---------------- FC: split-K MFMA, D = [16 n][16 oo] ----------------------
// featsT [br][16][256][576]; fcw [10][442368] with k = br*147456 + c*576 + pth
__global__ __launch_bounds__(64) void fc_mfma_kernel(
    const float* __restrict__ featsT, const float* __restrict__ fcw,
    float* __restrict__ partial) {
  const int blk = blockIdx.x;  // 864 blocks, 512 k each (16 chunks of 32)
  const int lane = threadIdx.x;
  const int mrow = lane & 15;  // n for A, oo for B
  const int slot = lane >> 4;
  const int slot8 = slot * 8;
  const int k0base = blk * 512;

  f32x4 acc = {0.f, 0.f, 0.f, 0.f};
  float4 z4 = make_float4(0.f, 0.f, 0.f, 0.f);
  for (int cc = 0; cc < 16; ++cc) {
    int k0 = k0base + cc * 32;
    int br = k0 / 147456;
    int rb = k0 - br * 147456;
    int c = rb / 576;
    int pth = rb - c * 576;
    const float* ap =
        featsT + (((size_t)(br * 16 + mrow) * 256 + c) * 576 + pth + slot8);
    float4 a0 = *reinterpret_cast<const float4*>(ap);
    float4 a1q = *reinterpret_cast<const float4*>(ap + 4);
    float4 b0 = z4, b1q = z4;
    if (mrow < 10) {
      const float* bp = fcw + (size_t)mrow * 442368 + k0 + slot8;
      b0 = *reinterpret_cast<const float4*>(bp);
      b1q = *reinterpret_cast<const float4*>(bp + 4);
    }
    float af[8] = {a0.x, a0.y, a0.z, a0.w, a1q.x, a1q.y, a1q.z, a1q.w};
    float bf[8] = {b0.x, b0.y, b0.z, b0.w, b1q.x, b1q.y, b1q.z, b1q.w};
    unsigned short ahv[8], alv[8], bhv[8], blv[8];
#pragma unroll
    for (int j = 0; j < 8; j++) {
      bsplit(af[j], ahv[j], alv[j]);
      bsplit(bf[j], bhv[j], blv[j]);
    }
    bf16x8 ah = *reinterpret_cast<bf16x8*>(ahv);
    bf16x8 al = *reinterpret_cast<bf16x8*>(alv);
    bf16x8 bh = *reinterpret_cast<bf16x8*>(bhv);
    bf16x8 bl = *reinterpret_cast<bf16x8*>(blv);
    acc = __builtin_amdgcn_mfma_f32_16x16x32_bf16(ah, bh, acc, 0, 0, 0);
    acc = __builtin_amdgcn_mfma_f32_16x16x32_bf16(ah, bl, acc, 0, 0, 0);
    acc = __builtin_amdgcn_mfma_f32_16x16x32_bf16(al, bh, acc, 0, 0, 0);
  }
#pragma unroll
  for (int rg = 0; rg < 4; rg++)
    partial[(size_t)blk * 256 + (slot * 4 + rg) * 16 + mrow] = acc[rg];
}

__global__ __launch_bounds__(64) void fc_final_kernel(
    const float* __restrict__ partial, const float* __restrict__ fcb,
    float* __restrict__ outp) {
  const int n = blockIdx.x / 10, oo = blockIdx.x % 10;
  const int lane = threadIdx.x;
  float s = 0.f;
  for (int b = lane; b < 864; b += 64)
    s += partial[(size_t)b * 256 + n * 16 + oo];
#pragma unroll
  for (int off = 32; off > 0; off >>= 1) s += __shfl_down(s, off, 64);
  if (lane == 0) outp[n * 10 + oo] = s + fcb[oo];
}

// ---------------------------------------------------------------------------
extern "C" void kernel_launch(void* const* d_in, const int* in_sizes, int n_in,
                              void* d_out, int out_size, void* d_ws,
                              size_t ws_size, hipStream_t stream) {
  const float* x   = (const float*)d_in[0];
  const float* w1  = (const float*)d_in[1];
  const float* w2  = (const float*)d_in[2];
  const float* w3  = (const float*)d_in[3];
  const float* tri = (const float*)d_in[4];
  const float* fcw = (const float*)d_in[5];
  const float* fcb = (const float*)d_in[6];
  float* out = (float*)d_out;

  float* ws = (float*)d_ws;
  float* a1     = ws;                 // 7,077,888
  float* a2     = a1 + 7077888;       // 3,538,944
  float* featsT = a2 + 3538944;       // 7,077,888  [br][n][256][576]
  float* s1     = featsT + 7077888;   // 192
  float* s2     = s1 + 192;           // 384
  float* s3     = s2 + 384;           // 768
  unsigned short* bw1h = (unsigned short*)(s3 + 768);    // 6,144 ushorts
  unsigned short* bw1l = bw1h + 6144;
  unsigned short* bph2 = bw1l + 6144;                    // 221,184
  unsigned short* bpl2 = bph2 + 221184;
  unsigned short* bph3 = bpl2 + 221184;                  // 884,736
  unsigned short* bpl3 = bph3 + 884736;
  float* partial = (float*)(bpl3 + 884736);              // 221,184 floats

  sw2_kernel<<<dim3(6), dim3(256), 0, stream>>>(w1, w2, w3, s1, s2, s3);
  pack_w1_kernel<<<dim3(24), dim3(256), 0, stream>>>(w1, bw1h, bw1l);
  pack_w_kernel<64, 128><<<dim3(128, 1, 3), dim3(256), 0, stream>>>(w2, bph2,
                                                                    bpl2);
  pack_w_kernel<128, 256><<<dim3(256, 1, 3), dim3(256), 0, stream>>>(w3, bph3,
                                                                     bpl3);

  layer1_kernel<<<dim3(144, 16, 3), dim3(256), 0, stream>>>(x, bw1h, bw1l, s1,
                                                            tri, a1);
  mfma_rbf3<64, 128, 48, 63, 1, 1>
      <<<dim3(72, 16, 3), dim3(256), 0, stream>>>(a1, bph2, bpl2, s2, tri, a2);
  mfma_rbf3<128, 256, 24, 152, 0, 2>
      <<<dim3(18, 16, 3), dim3(256), 0, stream>>>(a2, bph3, bpl3, s3, tri,
                                                  featsT);
  fc_mfma_kernel<<<dim3(864), dim3(64), 0, stream>>>(featsT, fcw, partial);
  fc_final_kernel<<<dim3(160), dim3(64), 0, stream>>>(partial, fcb, out);
}

// Round 10
// 120.427 us; speedup vs baseline: 4.4942x; 1.2487x over previous
//
#include <hip/hip_runtime.h>
#include <hip/hip_bf16.h>
#include <math.h>

typedef __attribute__((ext_vector_type(8))) short bf16x8;
typedef __attribute__((ext_vector_type(4))) float f32x4;

__device__ __forceinline__ void bsplit(float f, unsigned short& h,
                                       unsigned short& l) {
  __hip_bfloat16 hb = __float2bfloat16(f);
  float hf = __bfloat162float(hb);
  __hip_bfloat16 lb = __float2bfloat16(f - hf);
  h = *reinterpret_cast<unsigned short*>(&hb);
  l = *reinterpret_cast<unsigned short*>(&lb);
}

// ---------------- |w|^2 per filter row: one wave per row -------------------
// rows: 0..191 -> w1 (len 25), 192..575 -> w2 (len 576), 576..1343 -> w3
// (len 1152). 336 blocks x 256 thr = 1344 waves.
__global__ __launch_bounds__(256) void sw2_kernel(
    const float* __restrict__ w1, const float* __restrict__ w2,
    const float* __restrict__ w3,
    float* __restrict__ s1, float* __restrict__ s2, float* __restrict__ s3) {
  const int wid = blockIdx.x * 4 + (threadIdx.x >> 6);
  const int lane = threadIdx.x & 63;
  const float* r;
  float* dst;
  int len;
  if (wid < 192) {
    r = w1 + wid * 25;
    dst = s1 + wid;
    len = 25;
  } else if (wid < 576) {
    int u = wid - 192;
    r = w2 + u * 576;
    dst = s2 + u;
    len = 576;
  } else {
    int u = wid - 576;
    r = w3 + (size_t)u * 1152;
    dst = s3 + u;
    len = 1152;
  }
  float s = 0.f;
  for (int i = lane; i < len; i += 64) {
    float v = r[i];
    s += v * v;
  }
#pragma unroll
  for (int off = 32; off > 0; off >>= 1) s += __shfl_down(s, off, 64);
  if (lane == 0) *dst = s;
}

// ---------------- pack w1 into B-fragment layout [br][col(64)][k(32)] ------
__global__ __launch_bounds__(256) void pack_w1_kernel(
    const float* __restrict__ w1, unsigned short* __restrict__ bh,
    unsigned short* __restrict__ bl) {
  int idx = blockIdx.x * 256 + threadIdx.x;  // 3*64*32 = 6144
  if (idx >= 6144) return;
  int k = idx & 31;
  int col = (idx >> 5) & 63;
  int br = idx >> 11;
  float f = (k < 25) ? w1[(br * 64 + col) * 25 + k] : 0.f;
  unsigned short h, l;
  bsplit(f, h, l);
  bh[idx] = h;
  bl[idx] = l;
}

// ---------------- pack conv weights (layers 2/3), split hi/lo --------------
template <int CIN, int COUT>
__global__ __launch_bounds__(256) void pack_w_kernel(
    const float* __restrict__ w, unsigned short* __restrict__ bph,
    unsigned short* __restrict__ bpl) {
  constexpr int K = CIN * 9;
  constexpr int CC = CIN / 32;
  const int n = blockIdx.x, br = blockIdx.z;
  const int t = threadIdx.x;
  __shared__ float row[K];
  const float* src = w + ((size_t)br * COUT + n) * K;
  for (int i = t; i < K; i += 256) row[i] = src[i];
  __syncthreads();
  for (int i = t; i < K; i += 256) {
    int kpos = i / CIN;
    int e = i - kpos * CIN;  // = c
    float f = row[e * 9 + kpos];
    unsigned short h, l;
    bsplit(f, h, l);
    size_t oidx =
        (((size_t)br * 9 * CC + (size_t)kpos * CC + (e >> 5)) * COUT + n) * 32 +
        (e & 31);
    bph[oidx] = h;
    bpl[oidx] = l;
  }
}

// ---------------- Layer 1: MFMA split-bf16 5x5 conv, crelu(31), pool -------
__global__ __launch_bounds__(256) void layer1_kernel(
    const float* __restrict__ x,             // [16][3][96][96]
    const unsigned short* __restrict__ bw1h, // [3][64][32]
    const unsigned short* __restrict__ bw1l,
    const float* __restrict__ sw2v,          // [3][64]
    const float* __restrict__ tri,
    float* __restrict__ a1)                  // [3][16][48][48][64]
{
  const int gidx = blockIdx.x;  // 12 x 12 tiles
  const int gy = gidx / 12, gx = gidx % 12;
  const int n = blockIdx.y, br = blockIdx.z;
  const int t = threadIdx.x;
  const int lane = t & 63, wid = t >> 6;

  __shared__ __align__(16) float win[12][12];
  __shared__ float sp2s[64];
  __shared__ float sw2s[64];
  __shared__ __align__(16) float dmat[64][68];

  const int y0 = gy * 8 - 2, x0 = gx * 8 - 2;
  const float* xb = x + ((size_t)(n * 3 + br)) * 96 * 96;
  if (t < 144) {
    int wy = t / 12, wx = t - (t / 12) * 12;
    int y = y0 + wy, xx = x0 + wx;
    float v = 0.f;
    if (y >= 0 && y < 96 && xx >= 0 && xx < 96) v = xb[y * 96 + xx];
    win[wy][wx] = v;
  }
  if (t >= 192) sw2s[t - 192] = sw2v[br * 64 + (t - 192)];
  __syncthreads();

  if (t < 64) {
    int py = t >> 3, px = t & 7;
    float s = 0.f;
#pragma unroll
    for (int ky = 0; ky < 5; ky++)
#pragma unroll
      for (int kx = 0; kx < 5; kx++) {
        float v = win[py + ky][px + kx];
        s += v * v;
      }
    sp2s[t] = s;
  }

  // ---- A fragment: patch row = pixel (lane&15), k-slot = lane>>4 ----
  const int mrow = lane & 15;
  const int slot = lane >> 4;
  const int pixel = wid * 16 + mrow;
  const int ppy = pixel >> 3, ppx = pixel & 7;
  unsigned short ahv[8], alv[8];
#pragma unroll
  for (int j = 0; j < 8; j++) {
    int k = slot * 8 + j;
    float v = 0.f;
    if (k < 25) {
      int ky = (k * 205) >> 10;  // k/5 exact for k<32
      int kx = k - ky * 5;
      v = win[ppy + ky][ppx + kx];
    }
    bsplit(v, ahv[j], alv[j]);
  }
  bf16x8 ah = *reinterpret_cast<bf16x8*>(ahv);
  bf16x8 al = *reinterpret_cast<bf16x8*>(alv);

  // ---- B fragments (4 N-tiles of 16 ch) + 12 MFMAs ----
  f32x4 acc[4];
  f32x4 zz = {0.f, 0.f, 0.f, 0.f};
#pragma unroll
  for (int nt = 0; nt < 4; nt++) acc[nt] = zz;
#pragma unroll
  for (int nt = 0; nt < 4; nt++) {
    const int off = ((br * 64 + nt * 16 + mrow) << 5) + (slot << 3);
    bf16x8 bh = *reinterpret_cast<const bf16x8*>(bw1h + off);
    bf16x8 bl = *reinterpret_cast<const bf16x8*>(bw1l + off);
    acc[nt] = __builtin_amdgcn_mfma_f32_16x16x32_bf16(ah, bh, acc[nt], 0, 0, 0);
    acc[nt] = __builtin_amdgcn_mfma_f32_16x16x32_bf16(ah, bl, acc[nt], 0, 0, 0);
    acc[nt] = __builtin_amdgcn_mfma_f32_16x16x32_bf16(al, bh, acc[nt], 0, 0, 0);
  }
  __syncthreads();  // sp2s ready

  // ---- d matrix ----
  const float w_ = tri[br * 3 + 0];
  const int rgrp = slot * 4;
#pragma unroll
  for (int nt = 0; nt < 4; nt++) {
    const int ch = nt * 16 + mrow;
    const float sw = sw2s[ch];
#pragma unroll
    for (int rg = 0; rg < 4; rg++) {
      const int p = wid * 16 + rgrp + rg;
      float d2 = sp2s[p] + sw - 2.f * acc[nt][rg];
      dmat[p][ch] = sqrtf(fmaxf(d2, 1e-12f));
    }
  }
  // wave-local from here: each wave reads only its own 16 dmat rows

  // ---- per-pixel threshold: cheap w-path + rare radix fallback ----
  float thrv[16];
  unsigned int need = 0;
#pragma unroll
  for (int i = 0; i < 16; i++) {
    float v = dmat[wid * 16 + i][lane];
    int cnt = __popcll(__ballot(v >= w_));
    if (cnt >= 32) thrv[i] = w_;
    else need |= (1u << i);
  }
  if (need) {
#pragma unroll
    for (int i = 0; i < 16; i++) {
      if (!((need >> i) & 1)) continue;
      unsigned int key = __float_as_uint(dmat[wid * 16 + i][lane]);
      unsigned int pre = 0;
      int rem = 31;
      for (int b = 30; b >= 0; --b) {
        unsigned int top = (pre >> b) | 1u;
        int cnt = __popcll(__ballot((key >> b) == top));
        if (cnt > rem) pre |= (1u << b);
        else rem -= cnt;
      }
      thrv[i] = __uint_as_float(pre);
    }
  }

  // ---- pool (wave wid = pool row wid), lane = channel ----
  const float A2[2][2] = {{0.9f, 0.93f}, {0.96f, 0.99f}};
#pragma unroll
  for (int g = 0; g < 4; g++) {
    float pooled = 0.f;
#pragma unroll
    for (int py = 0; py < 2; py++)
#pragma unroll
      for (int q = 0; q < 2; q++) {
        int pi = py * 8 + g * 2 + q;
        float d = dmat[wid * 16 + pi][lane];
        float th = fminf(thrv[pi], w_);
        float a = 1.f - ((d > th) ? w_ : d) / w_;
        pooled += a * A2[py][q];
      }
    a1[((((size_t)(br * 16 + n)) * 48 + (gy * 4 + wid)) * 48 + (gx * 4 + g)) *
           64 + lane] = pooled * 0.25f;
  }
}

// ---------------- Layers 2/3: MFMA split-bf16 RBF conv ---------------------
// POOL=1 -> out [3][16][GW][GW][COUT] (a2). POOL=0 -> TRANSPOSED feats
// [3][16][COUT][576] to match fc_w's native order.
template <int CIN, int COUT, int HIN, int KRANK, int POOL, int LIDX>
__global__ __launch_bounds__(256) void mfma_rbf3(
    const float* __restrict__ in,            // [3][16][HIN][HIN][CIN]
    const unsigned short* __restrict__ bph,  // packed hi
    const unsigned short* __restrict__ bpl,  // packed lo
    const float* __restrict__ sw2v,          // [3][COUT]
    const float* __restrict__ tri,
    float* __restrict__ out) {
  constexpr int CC = CIN / 32;
  constexpr int NCH = 9 * CC;
  constexpr int NT = COUT / 16;
  constexpr int NTW = NT / 4;
  constexpr int PADC = COUT + 4;
  constexpr int WIN_USH = 60 * CIN;
  constexpr int WIN_BYTES = 2 * WIN_USH * 2;
  constexpr int DMAT_BYTES = 32 * PADC * 4;
  constexpr int UNI_BYTES = WIN_BYTES > DMAT_BYTES ? WIN_BYTES : DMAT_BYTES;

  __shared__ __align__(16) char uni[UNI_BYTES];
  __shared__ float cellq[60][4];
  __shared__ float cellsum[60];
  __shared__ float sp2[32];
  __shared__ float thrs[32];
  __shared__ float sw2s[COUT];
  __shared__ int zflag;

  unsigned short* winh = (unsigned short*)uni;
  unsigned short* winl = winh + WIN_USH;
  float* dmat = (float*)uni;

  const int GX = HIN / 8;
  const int gy = blockIdx.x / GX, gx = blockIdx.x % GX;
  const int n = blockIdx.y, br = blockIdx.z;
  const int t = threadIdx.x;
  const int lane = t & 63;
  const int wvid = t >> 6;
  const int ng = wvid;

  const float w_ = tri[br * 3 + LIDX];
  const int y0 = gy * 4 - 1, x0 = gx * 8 - 1;
  const float* ib = in + ((size_t)(br * 16 + n)) * HIN * HIN * CIN;

  for (int i = t; i < COUT; i += 256) sw2s[i] = sw2v[br * COUT + i];
  if (t < 240) {
    const int cell = t >> 2, q = t & 3;
    const int wy = cell / 10, wx = cell - (cell / 10) * 10;
    const int y = y0 + wy, xx = x0 + wx;
    const bool ok = (y >= 0 && y < HIN && xx >= 0 && xx < HIN);
    const float* rp = ib + ((size_t)y * HIN + xx) * CIN + q * (CIN / 4);
    const int sx = (wx & 7) << 3;
    float ss = 0.f;
#pragma unroll
    for (int cq = 0; cq < CIN / 16; cq++) {
      float4 v = ok ? *reinterpret_cast<const float4*>(rp + cq * 4)
                    : make_float4(0.f, 0.f, 0.f, 0.f);
      unsigned short hh[4], ll[4];
      float fv[4] = {v.x, v.y, v.z, v.w};
#pragma unroll
      for (int j = 0; j < 4; j++) {
        float f = fv[j];
        ss += f * f;
        bsplit(f, hh[j], ll[j]);
      }
      int c = q * (CIN / 4) + cq * 4;
      int cst = c ^ sx;
      *reinterpret_cast<ushort4*>(&winh[cell * CIN + cst]) =
          make_ushort4(hh[0], hh[1], hh[2], hh[3]);
      *reinterpret_cast<ushort4*>(&winl[cell * CIN + cst]) =
          make_ushort4(ll[0], ll[1], ll[2], ll[3]);
    }
    cellq[cell][q] = ss;
  }
  __syncthreads();
  if (t < 60)
    cellsum[t] = cellq[t][0] + cellq[t][1] + cellq[t][2] + cellq[t][3];
  __syncthreads();
  if (t < 32) {
    int py = t >> 3, px = t & 7;
    float s = 0.f;
#pragma unroll
    for (int ky = 0; ky < 3; ky++)
#pragma unroll
      for (int kx = 0; kx < 3; kx++) s += cellsum[(py + ky) * 10 + px + kx];
    sp2[t] = s;
  }
  if (t == 0) {
    float s = 0.f;
    for (int i = 0; i < 60; i++) s += cellsum[i];
    zflag = (s == 0.f);
  }
  __syncthreads();

  // ---- zero-window fast path ---------------------------------------------
  if (zflag) {
    for (int col = t; col < COUT; col += 256)
      dmat[col] = sqrtf(fmaxf(sw2s[col], 1e-12f));
    __syncthreads();
    if (wvid == 0) {
      float v0, v1, v2, v3;
      if constexpr (COUT == 256) {
        float4 f = *reinterpret_cast<const float4*>(&dmat[lane * 4]);
        v0 = f.x; v1 = f.y; v2 = f.z; v3 = f.w;
      } else {
        float2 f = *reinterpret_cast<const float2*>(&dmat[lane * 2]);
        v0 = f.x; v1 = f.y; v2 = 0.f; v3 = 0.f;
      }
      int cnt = __popcll(__ballot(v0 >= w_)) + __popcll(__ballot(v1 >= w_));
      if constexpr (COUT == 256)
        cnt += __popcll(__ballot(v2 >= w_)) + __popcll(__ballot(v3 >= w_));
      float thr;
      if (cnt > KRANK) {
        thr = w_;
      } else {
        unsigned int k0 = __float_as_uint(v0), k1 = __float_as_uint(v1);
        unsigned int k2 = __float_as_uint(v2), k3 = __float_as_uint(v3);
        unsigned int pre = 0;
        int rem = KRANK;
        for (int b = 30; b >= 0; --b) {
          unsigned int top = (pre >> b) | 1u;
          int c = __popcll(__ballot((k0 >> b) == top)) +
                  __popcll(__ballot((k1 >> b) == top));
          if constexpr (COUT == 256)
            c += __popcll(__ballot((k2 >> b) == top)) +
                 __popcll(__ballot((k3 >> b) == top));
          if (c > rem) pre |= (1u << b);
          else rem -= c;
        }
        thr = __uint_as_float(pre);
      }
      if (lane == 0) thrs[0] = thr;
    }
    __syncthreads();
    const float th = fminf(thrs[0], w_);
    if (POOL) {
      const int GW = HIN / 2;
      float* ob = out + ((size_t)(br * 16 + n)) * GW * GW * COUT;
      for (int col = t; col < COUT; col += 256) {
        float d0 = dmat[col];
        float a = 1.f - ((d0 > th) ? w_ : d0) / w_;
        float po = 0.25f * (a * 0.9f + a * 0.93f + a * 0.96f + a * 0.99f);
#pragma unroll
        for (int q = 0; q < 8; q++) {
          int qy = q >> 2, qx = q & 3;
          ob[((size_t)((gy * 2 + qy) * GW + gx * 4 + qx)) * COUT + col] = po;
        }
      }
    } else {
      // transposed feats [col][576]
      float* ob = out + ((size_t)(br * 16 + n)) * COUT * 576;
      for (int col = t; col < COUT; col += 256) {
        float d0 = dmat[col];
        float a = 1.f - ((d0 > th) ? w_ : d0) / w_;
        float4 av = make_float4(a, a, a, a);
#pragma unroll
        for (int row = 0; row < 4; row++) {
          float* dst = ob + (size_t)col * 576 + (gy * 4 + row) * 24 + gx * 8;
          *reinterpret_cast<float4*>(dst) = av;
          *reinterpret_cast<float4*>(dst + 4) = av;
        }
      }
    }
    return;
  }

  // ---- conv: reg-dbuf B pipeline, 3-term split ---------------------------
  const int pix0 = lane & 15;
  const int g8 = (lane >> 4) << 3;
  const int ppy = pix0 >> 3, ppx = pix0 & 7;

  f32x4 acc[2][NTW];
  f32x4 zz = {0.f, 0.f, 0.f, 0.f};
#pragma unroll
  for (int mt = 0; mt < 2; mt++)
#pragma unroll
    for (int nt = 0; nt < NTW; nt++) acc[mt][nt] = zz;

  const size_t bbase = (size_t)br * NCH;
  const int nb0 = ng * (NTW * 16) + pix0;

  bf16x8 bufA[2 * NTW], bufB[2 * NTW];

  auto loadB = [&](int chunk, bf16x8* dst) {
    const unsigned short* p0 = bph + ((bbase + chunk) * COUT + nb0) * 32 + g8;
    const unsigned short* p1 = bpl + ((bbase + chunk) * COUT + nb0) * 32 + g8;
#pragma unroll
    for (int nt = 0; nt < NTW; nt++) {
      dst[2 * nt] = *reinterpret_cast<const bf16x8*>(p0 + nt * 512);
      dst[2 * nt + 1] = *reinterpret_cast<const bf16x8*>(p1 + nt * 512);
    }
  };

  auto compute = [&](int chunk, bf16x8* b) {
    const int kpos = chunk / CC, cc = chunk - (chunk / CC) * CC;
    const int ky = kpos / 3, kx = kpos - (kpos / 3) * 3;
    const int wx = ppx + kx;
    const int sx = (wx & 7) << 3;
    const int cbase = ((cc << 5) + g8) ^ sx;
#pragma unroll
    for (int mt = 0; mt < 2; mt++) {
      const int r0 = (mt * 2 + ppy + ky) * 10 + wx;
      bf16x8 ah = *reinterpret_cast<const bf16x8*>(&winh[r0 * CIN + cbase]);
      bf16x8 al = *reinterpret_cast<const bf16x8*>(&winl[r0 * CIN + cbase]);
#pragma unroll
      for (int nt = 0; nt < NTW; nt++) {
        acc[mt][nt] = __builtin_amdgcn_mfma_f32_16x16x32_bf16(
            ah, b[2 * nt], acc[mt][nt], 0, 0, 0);
        acc[mt][nt] = __builtin_amdgcn_mfma_f32_16x16x32_bf16(
            ah, b[2 * nt + 1], acc[mt][nt], 0, 0, 0);
        acc[mt][nt] = __builtin_amdgcn_mfma_f32_16x16x32_bf16(
            al, b[2 * nt], acc[mt][nt], 0, 0, 0);
      }
    }
  };

  loadB(0, bufA);
  for (int ch = 0; ch < NCH; ch += 2) {
    loadB(ch + 1, bufB);
    compute(ch, bufA);
    if (ch + 2 < NCH) loadB(ch + 2, bufA);
    compute(ch + 1, bufB);
  }

  __syncthreads();  // conv reads of win done (alias!), sp2 visible

  const int rgrp = (lane >> 4) << 2;
#pragma unroll
  for (int mt = 0; mt < 2; mt++) {
    const int prow = mt * 16 + rgrp;
#pragma unroll
    for (int nt = 0; nt < NTW; nt++) {
      const int col = ng * (NTW * 16) + nt * 16 + pix0;
      const float sw = sw2s[col];
#pragma unroll
      for (int rg = 0; rg < 4; rg++) {
        const int pix = prow + rg;
        float d2 = sp2[pix] + sw - 2.f * acc[mt][nt][rg];
        dmat[pix * PADC + col] = sqrtf(fmaxf(d2, 1e-12f));
      }
    }
  }
  __syncthreads();

  for (int i = 0; i < 8; i++) {
    const int p = wvid * 8 + i;
    float v0, v1, v2, v3;
    if constexpr (COUT == 256) {
      float4 f = *reinterpret_cast<const float4*>(&dmat[p * PADC + lane * 4]);
      v0 = f.x; v1 = f.y; v2 = f.z; v3 = f.w;
    } else {
      float2 f = *reinterpret_cast<const float2*>(&dmat[p * PADC + lane * 2]);
      v0 = f.x; v1 = f.y; v2 = 0.f; v3 = 0.f;
    }
    int cnt = __popcll(__ballot(v0 >= w_)) + __popcll(__ballot(v1 >= w_));
    if constexpr (COUT == 256)
      cnt += __popcll(__ballot(v2 >= w_)) + __popcll(__ballot(v3 >= w_));
    if (cnt > KRANK) {
      if (lane == 0) thrs[p] = w_;
      continue;
    }
    unsigned int k0 = __float_as_uint(v0), k1 = __float_as_uint(v1);
    unsigned int k2 = __float_as_uint(v2), k3 = __float_as_uint(v3);
    unsigned int pre = 0;
    int rem = KRANK;
    for (int b = 30; b >= 0; --b) {
      unsigned int top = (pre >> b) | 1u;
      int c = __popcll(__ballot((k0 >> b) == top)) +
              __popcll(__ballot((k1 >> b) == top));
      if constexpr (COUT == 256)
        c += __popcll(__ballot((k2 >> b) == top)) +
             __popcll(__ballot((k3 >> b) == top));
      if (c > rem) pre |= (1u << b);
      else rem -= c;
    }
    if (lane == 0) thrs[p] = __uint_as_float(pre);
  }
  __syncthreads();

  if (POOL) {
    const int GW = HIN / 2;
    float* ob = out + ((size_t)(br * 16 + n)) * GW * GW * COUT;
    for (int i = t; i < 8 * COUT; i += 256) {
      int q = i / COUT;
      int ch = i - q * COUT;
      int qy = q >> 2, qx = q & 3;
      int p00 = qy * 16 + qx * 2;
      float d00 = dmat[p00 * PADC + ch];
      float d01 = dmat[(p00 + 1) * PADC + ch];
      float d10 = dmat[(p00 + 8) * PADC + ch];
      float d11 = dmat[(p00 + 9) * PADC + ch];
      float t00 = fminf(thrs[p00], w_);
      float t01 = fminf(thrs[p00 + 1], w_);
      float t10 = fminf(thrs[p00 + 8], w_);
      float t11 = fminf(thrs[p00 + 9], w_);
      float a00 = 1.f - ((d00 > t00) ? w_ : d00) / w_;
      float a01 = 1.f - ((d01 > t01) ? w_ : d01) / w_;
      float a10 = 1.f - ((d10 > t10) ? w_ : d10) / w_;
      float a11 = 1.f - ((d11 > t11) ? w_ : d11) / w_;
      float po =
          0.25f * (a00 * 0.9f + a01 * 0.93f + a10 * 0.96f + a11 * 0.99f);
      ob[((size_t)((gy * 2 + qy) * GW + gx * 4 + qx)) * COUT + ch] = po;
    }
  } else {
    // transposed feats [ch][576]
    float* ob = out + ((size_t)(br * 16 + n)) * COUT * 576;
    for (int item = t; item < COUT * 4; item += 256) {
      int ch = item & (COUT - 1);
      int rowq = item >> 8;
      float vals[8];
#pragma unroll
      for (int px = 0; px < 8; px++) {
        int p = rowq * 8 + px;
        float d = dmat[p * PADC + ch];
        float tt = fminf(thrs[p], w_);
        vals[px] = 1.f - ((d > tt) ? w_ : d) / w_;
      }
      float* dst = ob + (size_t)ch * 576 + (gy * 4 + rowq) * 24 + gx * 8;
      *reinterpret_cast<float4*>(dst) =
          make_float4(vals[0], vals[1], vals[2], vals[3]);
      *reinterpret_cast<float4*>(dst + 4) =
          make_float4(vals[4], vals[5], vals[6], vals[7]);
    }
  }
}

// ---------------- FC: split-K MFMA, D = [16 n][16 oo] ----------------------
// featsT [br][16][256][576]; fcw [10][442368] with k = br*147456 + c*576 + pth
__global__ __launch_bounds__(64) void fc_mfma_kernel(
    const float* __restrict__ featsT, const float* __restrict__ fcw,
    float* __restrict__ partial) {
  const int blk = blockIdx.x;  // 864 blocks, 512 k each (16 chunks of 32)
  const int lane = threadIdx.x;
  const int mrow = lane & 15;  // n for A, oo for B
  const int slot = lane >> 4;
  const int slot8 = slot * 8;
  const int k0base = blk * 512;

  f32x4 acc = {0.f, 0.f, 0.f, 0.f};
  float4 z4 = make_float4(0.f, 0.f, 0.f, 0.f);
  for (int cc = 0; cc < 16; ++cc) {
    int k0 = k0base + cc * 32;
    int br = k0 / 147456;
    int rb = k0 - br * 147456;
    int c = rb / 576;
    int pth = rb - c * 576;
    const float* ap =
        featsT + (((size_t)(br * 16 + mrow) * 256 + c) * 576 + pth + slot8);
    float4 a0 = *reinterpret_cast<const float4*>(ap);
    float4 a1q = *reinterpret_cast<const float4*>(ap + 4);
    float4 b0 = z4, b1q = z4;
    if (mrow < 10) {
      const float* bp = fcw + (size_t)mrow * 442368 + k0 + slot8;
      b0 = *reinterpret_cast<const float4*>(bp);
      b1q = *reinterpret_cast<const float4*>(bp + 4);
    }
    float af[8] = {a0.x, a0.y, a0.z, a0.w, a1q.x, a1q.y, a1q.z, a1q.w};
    float bf[8] = {b0.x, b0.y, b0.z, b0.w, b1q.x, b1q.y, b1q.z, b1q.w};
    unsigned short ahv[8], alv[8], bhv[8], blv[8];
#pragma unroll
    for (int j = 0; j < 8; j++) {
      bsplit(af[j], ahv[j], alv[j]);
      bsplit(bf[j], bhv[j], blv[j]);
    }
    bf16x8 ah = *reinterpret_cast<bf16x8*>(ahv);
    bf16x8 al = *reinterpret_cast<bf16x8*>(alv);
    bf16x8 bh = *reinterpret_cast<bf16x8*>(bhv);
    bf16x8 bl = *reinterpret_cast<bf16x8*>(blv);
    acc = __builtin_amdgcn_mfma_f32_16x16x32_bf16(ah, bh, acc, 0, 0, 0);
    acc = __builtin_amdgcn_mfma_f32_16x16x32_bf16(ah, bl, acc, 0, 0, 0);
    acc = __builtin_amdgcn_mfma_f32_16x16x32_bf16(al, bh, acc, 0, 0, 0);
  }
#pragma unroll
  for (int rg = 0; rg < 4; rg++)
    partial[(size_t)blk * 256 + (slot * 4 + rg) * 16 + mrow] = acc[rg];
}

__global__ __launch_bounds__(64) void fc_final_kernel(
    const float* __restrict__ partial, const float* __restrict__ fcb,
    float* __restrict__ outp) {
  const int n = blockIdx.x / 10, oo = blockIdx.x % 10;
  const int lane = threadIdx.x;
  float s = 0.f;
  for (int b = lane; b < 864; b += 64)
    s += partial[(size_t)b * 256 + n * 16 + oo];
#pragma unroll
  for (int off = 32; off > 0; off >>= 1) s += __shfl_down(s, off, 64);
  if (lane == 0) outp[n * 10 + oo] = s + fcb[oo];
}

// ---------------------------------------------------------------------------
extern "C" void kernel_launch(void* const* d_in, const int* in_sizes, int n_in,
                              void* d_out, int out_size, void* d_ws,
                              size_t ws_size, hipStream_t stream) {
  const float* x   = (const float*)d_in[0];
  const float* w1  = (const float*)d_in[1];
  const float* w2  = (const float*)d_in[2];
  const float* w3  = (const float*)d_in[3];
  const float* tri = (const float*)d_in[4];
  const float* fcw = (const float*)d_in[5];
  const float* fcb = (const float*)d_in[6];
  float* out = (float*)d_out;

  float* ws = (float*)d_ws;
  float* a1     = ws;                 // 7,077,888
  float* a2     = a1 + 7077888;       // 3,538,944
  float* featsT = a2 + 3538944;       // 7,077,888  [br][n][256][576]
  float* s1     = featsT + 7077888;   // 192
  float* s2     = s1 + 192;           // 384
  float* s3     = s2 + 384;           // 768
  unsigned short* bw1h = (unsigned short*)(s3 + 768);    // 6,144 ushorts
  unsigned short* bw1l = bw1h + 6144;
  unsigned short* bph2 = bw1l + 6144;                    // 221,184
  unsigned short* bpl2 = bph2 + 221184;
  unsigned short* bph3 = bpl2 + 221184;                  // 884,736
  unsigned short* bpl3 = bph3 + 884736;
  float* partial = (float*)(bpl3 + 884736);              // 221,184 floats

  sw2_kernel<<<dim3(336), dim3(256), 0, stream>>>(w1, w2, w3, s1, s2, s3);
  pack_w1_kernel<<<dim3(24), dim3(256), 0, stream>>>(w1, bw1h, bw1l);
  pack_w_kernel<64, 128><<<dim3(128, 1, 3), dim3(256), 0, stream>>>(w2, bph2,
                                                                    bpl2);
  pack_w_kernel<128, 256><<<dim3(256, 1, 3), dim3(256), 0, stream>>>(w3, bph3,
                                                                     bpl3);

  layer1_kernel<<<dim3(144, 16, 3), dim3(256), 0, stream>>>(x, bw1h, bw1l, s1,
                                                            tri, a1);
  mfma_rbf3<64, 128, 48, 63, 1, 1>
      <<<dim3(72, 16, 3), dim3(256), 0, stream>>>(a1, bph2, bpl2, s2, tri, a2);
  mfma_rbf3<128, 256, 24, 152, 0, 2>
      <<<dim3(18, 16, 3), dim3(256), 0, stream>>>(a2, bph3, bpl3, s3, tri,
                                                  featsT);
  fc_mfma_kernel<<<dim3(864), dim3(64), 0, stream>>>(featsT, fcw, partial);
  fc_final_kernel<<<dim3(160), dim3(64), 0, stream>>>(partial, fcb, out);
}